// Round 7
// baseline (428.309 us; speedup 1.0000x reference)
//
#include <hip/hip_runtime.h>
#include <stdint.h>

#define S_LEN 2048
#define NB 32
#define NE 512
#define NU 512
#define NP 256

typedef __bf16 bf16;
typedef __bf16 bf16x8 __attribute__((ext_vector_type(8)));
typedef __bf16 bf16x4 __attribute__((ext_vector_type(4)));
typedef float f32x4 __attribute__((ext_vector_type(4)));
typedef float f32x8 __attribute__((ext_vector_type(8)));

__device__ __forceinline__ void gload16(const void* g, void* l) {
    __builtin_amdgcn_global_load_lds(
        (__attribute__((address_space(1))) void*)g,
        (__attribute__((address_space(3))) void*)l, 16, 0, 0);
}

// DPP helpers (HW-verified rounds 4-6):
//   0x111 row_shr:1 -> lane i reads i-1 ; 0x101 row_shl:1 -> lane i reads i+1
__device__ __forceinline__ float dpp_shr1_z(float x) {
    return __builtin_bit_cast(float, __builtin_amdgcn_update_dpp(
        0, __builtin_bit_cast(int, x), 0x111, 0xF, 0xF, true));
}
__device__ __forceinline__ float dpp_shl1_z(float x) {
    return __builtin_bit_cast(float, __builtin_amdgcn_update_dpp(
        0, __builtin_bit_cast(int, x), 0x101, 0xF, 0xF, true));
}

// Stage a 128-row x 32-col bf16 tile (row stride SR elems) into an 8KB LDS
// buffer; self-inverse k-quad permutation (2-way bank spread = free).
__device__ __forceinline__ void stage_tile(const bf16* __restrict__ src, int SR,
                                           bf16* lds, int tid) {
#pragma unroll
    for (int rnd = 0; rnd < 2; ++rnd) {
        const int c = rnd * 256 + tid;
        const int row = c >> 2;
        const int q = (c & 3) ^ ((c >> 3) & 3);
        gload16(src + (size_t)row * SR + q * 8, lds + c * 8);
    }
}

// ---------------- kernel 0a: seq fp32 -> seqH/seqL bf16 (row-major) ---------
__global__ __launch_bounds__(256) void k_prep0(
    const float* __restrict__ seq, bf16* __restrict__ sH, bf16* __restrict__ sL)
{
    const size_t i = ((size_t)blockIdx.x * 256 + threadIdx.x) * 8;
    const f32x8 v = *(const f32x8*)(seq + i);
    bf16x8 h, l;
#pragma unroll
    for (int q = 0; q < 8; ++q) {
        const bf16 hb = (bf16)v[q];
        h[q] = hb;
        l[q] = (bf16)(v[q] - (float)hb);
    }
    *(bf16x8*)(sH + i) = h;
    *(bf16x8*)(sL + i) = l;
}

// ---------------- kernel 0b: w1 fp32 -> bf16 hi/lo --------------------------
__global__ __launch_bounds__(256) void k_wconv(
    const float* __restrict__ w1, bf16* __restrict__ wHi, bf16* __restrict__ wLo)
{
    const int i = (blockIdx.x * 256 + threadIdx.x) * 4;
    const float4 v = *(const float4*)(w1 + i);
    const float vv[4] = {v.x, v.y, v.z, v.w};
    bf16x4 oh, ol;
#pragma unroll
    for (int q = 0; q < 4; ++q) {
        const bf16 hb = (bf16)vv[q];
        oh[q] = hb;
        ol[q] = (bf16)(vv[q] - (float)hb);
    }
    *(bf16x4*)(wHi + i) = oh;
    *(bf16x4*)(wLo + i) = ol;
}

// ---------------- kernel 1: GEMM1 + silu + logits + softmax -----------------
// M-tile 64 rows/block (grid 1024 -> 4 blocks/CU), 1 m-tile per wave.
// A = seqH/seqL bf16 direct per-lane (pre-split, no conversion VALU).
// B = w1 hi/lo staged in LDS (double-buffered global_load_lds).
__global__ __launch_bounds__(256, 4) void k_gemm1(
    const bf16* __restrict__ seqH, const bf16* __restrict__ seqL,
    const bf16* __restrict__ w1H, const bf16* __restrict__ w1L,
    const float* __restrict__ b1v, const float* __restrict__ w2,
    const float* __restrict__ b2v, float* __restrict__ actions)
{
    __shared__ __align__(16) bf16 BhL[2][4096];
    __shared__ __align__(16) bf16 BlL[2][4096];
    const int tid = threadIdx.x;
    const int wid = tid >> 6;
    const int lane = tid & 63;
    const int lr = lane & 15, lg = lane >> 4;
    const int m0 = blockIdx.x << 6;

    const bf16* ahp = seqH + (size_t)(m0 + wid * 16 + lr) * NE + lg * 8;
    const bf16* alp = seqL + (size_t)(m0 + wid * 16 + lr) * NE + lg * 8;
    const int lroff = lr * 64 + (lg ^ ((lr >> 1) & 3)) * 16;

    float plog[3][4];
#pragma unroll
    for (int a = 0; a < 3; ++a)
#pragma unroll
        for (int q = 0; q < 4; ++q) plog[a][q] = 0.f;

    f32x4 acc[8];
    stage_tile(w1H, NE, BhL[0], tid);
    stage_tile(w1L, NE, BlL[0], tid);
    bf16x8 AaH = *(const bf16x8*)(ahp);
    bf16x8 AaL = *(const bf16x8*)(alp);
    bf16x8 AbH, AbL;

#define G1_BODY(g, buf, AcH, AcL, AnH, AnL) do {                              \
        __syncthreads();                                                      \
        if (((g) & 15) == 0) {                                                \
            _Pragma("unroll") for (int j = 0; j < 8; ++j)                     \
                acc[j] = (f32x4)(0.f);                                        \
        }                                                                     \
        bf16x8 bh[8], bl[8];                                                  \
        _Pragma("unroll") for (int j = 0; j < 8; ++j) {                       \
            bh[j] = *(const bf16x8*)((const char*)BhL[buf] + j * 1024 + lroff);\
            bl[j] = *(const bf16x8*)((const char*)BlL[buf] + j * 1024 + lroff);\
        }                                                                     \
        __syncthreads();                                                      \
        if ((g) < 63) {                                                       \
            const int gn = (g) + 1;                                           \
            const int u0n = (gn >> 4) << 7;                                   \
            const int k0n = (gn & 15) << 5;                                   \
            stage_tile(w1H + (size_t)u0n * NE + k0n, NE, BhL[(buf) ^ 1], tid);\
            stage_tile(w1L + (size_t)u0n * NE + k0n, NE, BlL[(buf) ^ 1], tid);\
            AnH = *(const bf16x8*)(ahp + k0n);                                \
            AnL = *(const bf16x8*)(alp + k0n);                                \
        }                                                                     \
        _Pragma("unroll") for (int j = 0; j < 8; ++j) {                       \
            acc[j] = __builtin_amdgcn_mfma_f32_16x16x32_bf16(AcH, bh[j], acc[j], 0, 0, 0); \
            acc[j] = __builtin_amdgcn_mfma_f32_16x16x32_bf16(AcH, bl[j], acc[j], 0, 0, 0); \
            acc[j] = __builtin_amdgcn_mfma_f32_16x16x32_bf16(AcL, bh[j], acc[j], 0, 0, 0); \
        }                                                                     \
        if (((g) & 15) == 15) {                                               \
            const int u0 = ((g) >> 4) << 7;                                   \
            _Pragma("unroll") for (int j = 0; j < 8; ++j) {                   \
                const int col = u0 + j * 16 + lr;                             \
                const float b1c = b1v[col];                                   \
                const float w20 = w2[col], w21 = w2[NU + col], w22 = w2[2 * NU + col]; \
                _Pragma("unroll") for (int q = 0; q < 4; ++q) {               \
                    const float x = acc[j][q] + b1c;                          \
                    const float hgate = x / (1.f + __expf(-x));               \
                    plog[0][q] = fmaf(hgate, w20, plog[0][q]);                \
                    plog[1][q] = fmaf(hgate, w21, plog[1][q]);                \
                    plog[2][q] = fmaf(hgate, w22, plog[2][q]);                \
                }                                                             \
            }                                                                 \
        }                                                                     \
    } while (0)

    for (int gg = 0; gg < 32; ++gg) {
        G1_BODY(2 * gg, 0, AaH, AaL, AbH, AbL);
        G1_BODY(2 * gg + 1, 1, AbH, AbL, AaH, AaL);
    }
#undef G1_BODY

#pragma unroll
    for (int m = 1; m < 16; m <<= 1) {
#pragma unroll
        for (int a = 0; a < 3; ++a)
#pragma unroll
            for (int q = 0; q < 4; ++q)
                plog[a][q] += __shfl_xor(plog[a][q], m);
    }
    const float bb0 = b2v[0], bb1 = b2v[1], bb2 = b2v[2];
    if (lr == 0) {
#pragma unroll
        for (int q = 0; q < 4; ++q) {
            const int row = m0 + wid * 16 + lg * 4 + q;
            const float l0 = plog[0][q] + bb0;
            const float l1 = plog[1][q] + bb1;
            const float l2 = plog[2][q] + bb2;
            const float mx = fmaxf(l0, fmaxf(l1, l2));
            const float e0 = __expf(l0 - mx), e1 = __expf(l1 - mx), e2 = __expf(l2 - mx);
            const float inv = 1.f / (e0 + e1 + e2);
            *(float4*)(actions + (size_t)row * 4) = make_float4(e0 * inv, e1 * inv, e2 * inv, 0.f);
        }
    }
}

// ---------------- fused kernel: scan (blocks 0..31) + prep transpose --------
// 5 waves per scan block: wave 4 = rs producer (one chunk ahead, DPP shr1),
// waves 0..3 = T consumers, one cell per lane; T[w+1] = lane+1 via DPP shl1.
union SPMem {
    float tile[64][65];                    // prep path (16.6 KB)
    struct {
        float4 actbuf[3][256];             // 12 KB
        float  sums[2][256][16];           // 32 KB
    } s;
};

__device__ __forceinline__ void rs_chunk(const float4* __restrict__ pb,
                                         float* __restrict__ so,
                                         float& rs, int lane)
{
    for (int w = 0; w < 32; ++w) {
        const int rtop = 255 - w * 8;
        const float4 e0 = pb[rtop],     e1 = pb[rtop - 1];
        const float4 e2 = pb[rtop - 2], e3 = pb[rtop - 3];
        const float4 e4 = pb[rtop - 4], e5 = pb[rtop - 5];
        const float4 e6 = pb[rtop - 6], e7 = pb[rtop - 7];
#define RS_STEP(E, k) do {                                                    \
        const float rsp = dpp_shr1_z(rs);                                     \
        const float s = (E).y * rsp;                                          \
        if (lane < 16) so[(rtop - (k)) * 16 + lane] = s;                      \
        rs = fmaf((E).x + (E).z, rs, s);                                      \
    } while (0)
        RS_STEP(e0, 0); RS_STEP(e1, 1); RS_STEP(e2, 2); RS_STEP(e3, 3);
        RS_STEP(e4, 4); RS_STEP(e5, 5); RS_STEP(e6, 6); RS_STEP(e7, 7);
#undef RS_STEP
    }
}

__device__ __forceinline__ void t_chunk(const float4* __restrict__ lb,
                                        const float* __restrict__ sp,
                                        float& T, bf16* __restrict__ obp,
                                        int tbase0, int w15)
{
    for (int w = 0; w < 32; ++w) {
        const int rtop = 255 - w * 8;
        const int tglob = tbase0 + rtop - 7;
        const float4 av0 = lb[rtop],     av1 = lb[rtop - 1];
        const float4 av2 = lb[rtop - 2], av3 = lb[rtop - 3];
        const float4 av4 = lb[rtop - 4], av5 = lb[rtop - 5];
        const float4 av6 = lb[rtop - 6], av7 = lb[rtop - 7];
        const float su0 = sp[rtop * 16],       su1 = sp[(rtop - 1) * 16];
        const float su2 = sp[(rtop - 2) * 16], su3 = sp[(rtop - 3) * 16];
        const float su4 = sp[(rtop - 4) * 16], su5 = sp[(rtop - 5) * 16];
        const float su6 = sp[(rtop - 6) * 16], su7 = sp[(rtop - 7) * 16];
        bf16x8 fr;
#define T_STEP(Av, Su, fi) do {                                               \
        const float a0 = (Av).x, a1 = (Av).y, a2 = (Av).z;                    \
        fr[fi] = (bf16)((a0 + a1) * T);                                       \
        const float nT = dpp_shl1_z(T);                                       \
        const float contrib = w15 ? (Su) : a0 * nT;                           \
        T = fmaf(a2, T, contrib);                                             \
    } while (0)
        T_STEP(av0, su0, 7); T_STEP(av1, su1, 6);
        T_STEP(av2, su2, 5); T_STEP(av3, su3, 4);
        T_STEP(av4, su4, 3); T_STEP(av5, su5, 2);
        T_STEP(av6, su6, 1); T_STEP(av7, su7, 0);
#undef T_STEP
        *(bf16x8*)(obp + tglob) = fr;
    }
}

__global__ __launch_bounds__(320) void k_scan_prep(
    const float* __restrict__ actions, bf16* __restrict__ wsT,
    const float* __restrict__ seq, bf16* __restrict__ tHi)
{
    __shared__ SPMem sm;
    const int tid = threadIdx.x;
    if (blockIdx.x < 32) {
        const int b = blockIdx.x;
        const int wid = tid >> 6;
        const int lane = tid & 63;
        const float4* actb = (const float4*)actions + (size_t)b * S_LEN;

        float rs = (lane == 0) ? 1.f : 0.f;
        float T = (wid == 0 && lane == 15) ? 1.f : 0.f;
        const int w15 = ((lane & 15) == 15) ? 1 : 0;
        bf16* obp = wsT + ((size_t)b * NP + wid * 64 + lane) * S_LEN;

        if (wid < 4) {
            gload16(actb + 1792 + wid * 64 + lane, &sm.s.actbuf[0][wid * 64]);
            gload16(actb + 1536 + wid * 64 + lane, &sm.s.actbuf[1][wid * 64]);
            asm volatile("s_waitcnt vmcnt(0)" ::: "memory");
        }
        __syncthreads();
        if (wid == 4) rs_chunk(sm.s.actbuf[0], &sm.s.sums[0][0][0], rs, lane);
        __syncthreads();

        int bufT = 0, bufP = 1, bufL = 2;
        for (int c = 0; c < 8; ++c) {
            if (wid < 4) {
                if (c < 6)
                    gload16(actb + (1280 - c * 256) + wid * 64 + lane,
                            &sm.s.actbuf[bufL][wid * 64]);
                t_chunk(sm.s.actbuf[bufT],
                        &sm.s.sums[c & 1][0][wid * 4 + (lane >> 4)],
                        T, obp, 1792 - c * 256, w15);
                asm volatile("s_waitcnt vmcnt(0)" ::: "memory");
            } else {
                if (c < 7)
                    rs_chunk(sm.s.actbuf[bufP], &sm.s.sums[(c + 1) & 1][0][0], rs, lane);
            }
            __syncthreads();
            const int t = bufT; bufT = bufP; bufP = bufL; bufL = t;
        }
        return;
    }
    // ---- prep transpose path (seq fp32 -> seqtH[b][e][s] bf16) ----
    const int bid = blockIdx.x - 32;
    const int b = bid >> 8;
    const int r = bid & 255;
    const int s0 = (r & 31) << 6;
    const int e0 = (r >> 5) << 6;
    const int tx = tid & 15, ty = (tid & 255) >> 4;
    const float* src = seq + ((size_t)b * S_LEN + s0) * NE + e0;
    if (tid < 256) {
#pragma unroll
        for (int i = 0; i < 4; ++i) {
            const int row = ty + i * 16;
            const float4 v = *(const float4*)(src + (size_t)row * NE + tx * 4);
            sm.tile[row][tx * 4 + 0] = v.x; sm.tile[row][tx * 4 + 1] = v.y;
            sm.tile[row][tx * 4 + 2] = v.z; sm.tile[row][tx * 4 + 3] = v.w;
        }
    }
    __syncthreads();
    if (tid < 256) {
        const int sx = tid & 7, ey = tid >> 3;
#pragma unroll
        for (int jj = 0; jj < 2; ++jj) {
            const int er = ey + jj * 32;
            bf16x8 oh;
#pragma unroll
            for (int q = 0; q < 8; ++q) oh[q] = (bf16)sm.tile[sx * 8 + q][er];
            *(bf16x8*)(tHi + ((size_t)b * NE + e0 + er) * S_LEN + s0 + sx * 8) = oh;
        }
    }
}

// ---------------- kernel 3: GEMM2 partials (2-way k-split, LDS-staged) ------
__global__ __launch_bounds__(256, 2) void k_gemm2(
    const bf16* __restrict__ wsT, const bf16* __restrict__ seqtH,
    float* __restrict__ part)
{
    __shared__ __align__(16) bf16 AL[2][4096];
    __shared__ __align__(16) bf16 BL[2][4096];
    const int tid = threadIdx.x;
    const int wid = tid >> 6;
    const int lane = tid & 63;
    const int lr = lane & 15, lg = lane >> 4;
    const int bid = blockIdx.x;
    const int b = bid >> 4;
    const int sub = bid & 15;
    const int kc = sub >> 3;
    const int p0 = ((sub >> 2) & 1) << 7;
    const int e0 = (sub & 3) << 7;

    const bf16* Abase = wsT + ((size_t)b * NP + p0) * S_LEN + kc * 1024;
    const bf16* Bbase = seqtH + ((size_t)b * NE + e0) * S_LEN + kc * 1024;
    const int lroff = lr * 64 + (lg ^ ((lr >> 1) & 3)) * 16;

    f32x4 acc[2][8];
#pragma unroll
    for (int i = 0; i < 2; ++i)
#pragma unroll
        for (int j = 0; j < 8; ++j) acc[i][j] = (f32x4)(0.f);

    stage_tile(Abase, S_LEN, AL[0], tid);
    stage_tile(Bbase, S_LEN, BL[0], tid);

#define G2_BODY(kt, buf) do {                                                 \
        __syncthreads();                                                      \
        bf16x8 af[2], bfv[8];                                                 \
        _Pragma("unroll") for (int i = 0; i < 2; ++i)                         \
            af[i] = *(const bf16x8*)((const char*)AL[buf]                     \
                     + (wid * 32 + i * 16) * 64 + lroff);                     \
        _Pragma("unroll") for (int j = 0; j < 8; ++j)                         \
            bfv[j] = *(const bf16x8*)((const char*)BL[buf] + j * 1024 + lroff);\
        __syncthreads();                                                      \
        if ((kt) < 31) {                                                      \
            stage_tile(Abase + ((kt) + 1) * 32, S_LEN, AL[(buf) ^ 1], tid);   \
            stage_tile(Bbase + ((kt) + 1) * 32, S_LEN, BL[(buf) ^ 1], tid);   \
        }                                                                     \
        _Pragma("unroll") for (int j = 0; j < 8; ++j) {                       \
            acc[0][j] = __builtin_amdgcn_mfma_f32_16x16x32_bf16(af[0], bfv[j], acc[0][j], 0, 0, 0); \
            acc[1][j] = __builtin_amdgcn_mfma_f32_16x16x32_bf16(af[1], bfv[j], acc[1][j], 0, 0, 0); \
        }                                                                     \
    } while (0)

    for (int kk = 0; kk < 16; ++kk) {
        G2_BODY(2 * kk, 0);
        G2_BODY(2 * kk + 1, 1);
    }
#undef G2_BODY

    float* obp = part + (((size_t)kc * NB + b) * NP + p0 + wid * 32) * NE + e0;
#pragma unroll
    for (int i = 0; i < 2; ++i)
#pragma unroll
        for (int j = 0; j < 8; ++j)
#pragma unroll
            for (int q = 0; q < 4; ++q)
                obp[(size_t)(i * 16 + lg * 4 + q) * NE + j * 16 + lr] = acc[i][j][q];
}

// ---------------- kernel 4: reduce the 2 partials ---------------------------
__global__ __launch_bounds__(256) void k_gred(
    const float* __restrict__ part, float* __restrict__ outp)
{
    const size_t i = ((size_t)blockIdx.x * 256 + threadIdx.x) * 4;
    const float4 p0 = *(const float4*)(part + i);
    const float4 p1 = *(const float4*)(part + ((size_t)NB * NP * NE) + i);
    *(float4*)(outp + i) = make_float4(p0.x + p1.x, p0.y + p1.y,
                                       p0.z + p1.z, p0.w + p1.w);
}

// ---------------- launch ----------------------------------------------------
// Workspace layout (sequential aliasing, total 162 MB):
//   [0,64M)    seqH  (prep0 -> gemm1)   then seqtH (scan_prep -> gemm2)
//   [64,128M)  seqL  (prep0 -> gemm1)   then wsT [64,96M) (scan_prep -> gemm2)
//   [128,160M) part
//   [160,161M) actions
//   [161,162M) w1H, w1L
extern "C" void kernel_launch(void* const* d_in, const int* in_sizes, int n_in,
                              void* d_out, int out_size, void* d_ws, size_t ws_size,
                              hipStream_t stream) {
    (void)in_sizes; (void)n_in; (void)out_size; (void)ws_size;
    const float* seq = (const float*)d_in[0];
    const float* w1  = (const float*)d_in[1];
    const float* b1  = (const float*)d_in[2];
    const float* w2  = (const float*)d_in[3];
    const float* b2  = (const float*)d_in[4];
    float* outp = (float*)d_out;

    char* ws = (char*)d_ws;
    bf16*  seqH    = (bf16*)(ws);                        // 64 MB
    bf16*  seqtH   = (bf16*)(ws);                        // alias (after gemm1)
    bf16*  seqL    = (bf16*)(ws + (64ull << 20));        // 64 MB
    bf16*  wsT     = (bf16*)(ws + (64ull << 20));        // alias (after gemm1)
    float* part    = (float*)(ws + (128ull << 20));      // 32 MB
    float* actions = (float*)(ws + (160ull << 20));      // 1 MB
    bf16*  w1H     = (bf16*)(ws + (161ull << 20));       // 512 KB
    bf16*  w1L     = (bf16*)(ws + (161ull << 20) + (512u << 10)); // 512 KB

    hipLaunchKernelGGL(k_wconv, dim3(256),   dim3(256), 0, stream, w1, w1H, w1L);
    hipLaunchKernelGGL(k_prep0, dim3(16384), dim3(256), 0, stream, seq, seqH, seqL);
    hipLaunchKernelGGL(k_gemm1, dim3(1024),  dim3(256), 0, stream,
                       seqH, seqL, w1H, w1L, b1, w2, b2, actions);
    hipLaunchKernelGGL(k_scan_prep, dim3(32 + 8192), dim3(320), 0, stream,
                       actions, wsT, seq, seqtH);
    hipLaunchKernelGGL(k_gemm2, dim3(512),  dim3(256), 0, stream, wsT, seqtH, part);
    hipLaunchKernelGGL(k_gred,  dim3(4096), dim3(256), 0, stream, part, outp);
}

// Round 8
// 380.168 us; speedup vs baseline: 1.1266x; 1.1266x over previous
//
#include <hip/hip_runtime.h>
#include <stdint.h>

#define S_LEN 2048
#define NB 32
#define NE 512
#define NU 512
#define NP 256

typedef __bf16 bf16;
typedef __bf16 bf16x8 __attribute__((ext_vector_type(8)));
typedef __bf16 bf16x4 __attribute__((ext_vector_type(4)));
typedef float f32x4 __attribute__((ext_vector_type(4)));
typedef float f32x8 __attribute__((ext_vector_type(8)));

__device__ __forceinline__ void gload16(const void* g, void* l) {
    __builtin_amdgcn_global_load_lds(
        (__attribute__((address_space(1))) void*)g,
        (__attribute__((address_space(3))) void*)l, 16, 0, 0);
}

// DPP helpers (HW-verified rounds 4-6)
__device__ __forceinline__ float dpp_shr1_z(float x) {
    return __builtin_bit_cast(float, __builtin_amdgcn_update_dpp(
        0, __builtin_bit_cast(int, x), 0x111, 0xF, 0xF, true));
}
__device__ __forceinline__ float dpp_shl1_z(float x) {
    return __builtin_bit_cast(float, __builtin_amdgcn_update_dpp(
        0, __builtin_bit_cast(int, x), 0x101, 0xF, 0xF, true));
}

// Stage a 128-row x 32-col bf16 tile (row stride SR) into 8KB LDS (256 thr).
__device__ __forceinline__ void stage_tile(const bf16* __restrict__ src, int SR,
                                           bf16* lds, int tid) {
#pragma unroll
    for (int rnd = 0; rnd < 2; ++rnd) {
        const int c = rnd * 256 + tid;
        const int row = c >> 2;
        const int q = (c & 3) ^ ((c >> 3) & 3);
        gload16(src + (size_t)row * SR + q * 8, lds + c * 8);
    }
}

// ---------------- kernel 0b: w1 fp32 -> bf16 hi/lo --------------------------
__global__ __launch_bounds__(256) void k_wconv(
    const float* __restrict__ w1, bf16* __restrict__ wHi, bf16* __restrict__ wLo)
{
    const int i = (blockIdx.x * 256 + threadIdx.x) * 4;
    const float4 v = *(const float4*)(w1 + i);
    const float vv[4] = {v.x, v.y, v.z, v.w};
    bf16x4 oh, ol;
#pragma unroll
    for (int q = 0; q < 4; ++q) {
        const bf16 hb = (bf16)vv[q];
        oh[q] = hb;
        ol[q] = (bf16)(vv[q] - (float)hb);
    }
    *(bf16x4*)(wHi + i) = oh;
    *(bf16x4*)(wLo + i) = ol;
}

// ---------------- kernel 1: GEMM1 + silu + logits + softmax -----------------
// 512 threads = 8 waves (wm 0..1 x wu 0..3). Wave owns 64 rows (4 m-frags) x
// 64 u (4 j-frags); block = 128 rows x 256 u; 2 u-panels (A re-read x2 only).
// A = seq fp32 per-lane, hi/lo in regs; B = w1 hi/lo in LDS (dbuf 2x32KB).
// ds:MFMA per kt = 8:48 -> MFMA-bound.
__device__ __forceinline__ void g1_stage(const bf16* __restrict__ w1H,
                                         const bf16* __restrict__ w1L,
                                         int g, bf16* dH, bf16* dL, int tid) {
#pragma unroll
    for (int rnd = 0; rnd < 2; ++rnd) {
        const int c = rnd * 512 + tid;
        const int row = c >> 2;
        const int q = (c & 3) ^ ((c >> 3) & 3);
        const size_t so = (size_t)((g >> 4) * 256 + row) * NE + (g & 15) * 32 + q * 8;
        gload16(w1H + so, dH + c * 8);
        gload16(w1L + so, dL + c * 8);
    }
}

__global__ __launch_bounds__(512, 2) void k_gemm1(
    const float* __restrict__ seq,
    const bf16* __restrict__ w1H, const bf16* __restrict__ w1L,
    const float* __restrict__ b1v, const float* __restrict__ w2,
    const float* __restrict__ b2v, float* __restrict__ actions)
{
    __shared__ __align__(16) bf16 BhL[2][8192];
    __shared__ __align__(16) bf16 BlL[2][8192];
    __shared__ float red[4][2][4][4][4][3];   // [wu][wm][i][lg][q][a]
    const int tid = threadIdx.x;
    const int wid = tid >> 6;
    const int wm = wid >> 2, wu = wid & 3;
    const int lane = tid & 63;
    const int lr = lane & 15, lg = lane >> 4;
    const int m0 = blockIdx.x << 7;

    const float* ar[4];
#pragma unroll
    for (int i = 0; i < 4; ++i)
        ar[i] = seq + (size_t)(m0 + wm * 64 + i * 16 + lr) * NE + lg * 8;
    const int lbase = (wu * 64 + lr) * 64 + (lg ^ ((lr >> 1) & 3)) * 16;

    float plog[3][4][4];
#pragma unroll
    for (int a = 0; a < 3; ++a)
#pragma unroll
        for (int i = 0; i < 4; ++i)
#pragma unroll
            for (int q = 0; q < 4; ++q) plog[a][i][q] = 0.f;

    f32x4 acc[4][4];
    g1_stage(w1H, w1L, 0, BhL[0], BlL[0], tid);
    f32x8 AC[4], AN[4];
#pragma unroll
    for (int i = 0; i < 4; ++i) AC[i] = *(const f32x8*)(ar[i]);

#define G1_BODY(g, buf, Ac, An) do {                                          \
        __syncthreads();                                                      \
        if (((g) & 15) == 0) {                                                \
            _Pragma("unroll") for (int i = 0; i < 4; ++i)                     \
            _Pragma("unroll") for (int j = 0; j < 4; ++j)                     \
                acc[i][j] = (f32x4)(0.f);                                     \
        }                                                                     \
        bf16x8 bh[4], bl[4];                                                  \
        _Pragma("unroll") for (int j = 0; j < 4; ++j) {                       \
            bh[j] = *(const bf16x8*)((const char*)BhL[buf] + j * 1024 + lbase);\
            bl[j] = *(const bf16x8*)((const char*)BlL[buf] + j * 1024 + lbase);\
        }                                                                     \
        __syncthreads();                                                      \
        if ((g) < 31) {                                                       \
            g1_stage(w1H, w1L, (g) + 1, BhL[(buf) ^ 1], BlL[(buf) ^ 1], tid); \
            const int ktn = ((g) + 1) & 15;                                   \
            _Pragma("unroll") for (int i = 0; i < 4; ++i)                     \
                An[i] = *(const f32x8*)(ar[i] + ktn * 32);                    \
        }                                                                     \
        bf16x8 Ah[4], Al[4];                                                  \
        _Pragma("unroll") for (int i = 0; i < 4; ++i)                         \
        _Pragma("unroll") for (int e = 0; e < 8; ++e) {                       \
            const bf16 hb = (bf16)Ac[i][e];                                   \
            Ah[i][e] = hb; Al[i][e] = (bf16)(Ac[i][e] - (float)hb);           \
        }                                                                     \
        _Pragma("unroll") for (int j = 0; j < 4; ++j)                         \
        _Pragma("unroll") for (int i = 0; i < 4; ++i) {                       \
            acc[i][j] = __builtin_amdgcn_mfma_f32_16x16x32_bf16(Ah[i], bh[j], acc[i][j], 0, 0, 0); \
            acc[i][j] = __builtin_amdgcn_mfma_f32_16x16x32_bf16(Ah[i], bl[j], acc[i][j], 0, 0, 0); \
            acc[i][j] = __builtin_amdgcn_mfma_f32_16x16x32_bf16(Al[i], bh[j], acc[i][j], 0, 0, 0); \
        }                                                                     \
        if (((g) & 15) == 15) {                                               \
            const int p = (g) >> 4;                                           \
            _Pragma("unroll") for (int j = 0; j < 4; ++j) {                   \
                const int col = p * 256 + wu * 64 + j * 16 + lr;              \
                const float b1c = b1v[col];                                   \
                const float w20 = w2[col], w21 = w2[NU + col], w22 = w2[2 * NU + col]; \
                _Pragma("unroll") for (int i = 0; i < 4; ++i)                 \
                _Pragma("unroll") for (int q = 0; q < 4; ++q) {               \
                    const float x = acc[i][j][q] + b1c;                       \
                    const float hg = x / (1.f + __expf(-x));                  \
                    plog[0][i][q] = fmaf(hg, w20, plog[0][i][q]);             \
                    plog[1][i][q] = fmaf(hg, w21, plog[1][i][q]);             \
                    plog[2][i][q] = fmaf(hg, w22, plog[2][i][q]);             \
                }                                                             \
            }                                                                 \
        }                                                                     \
    } while (0)

    for (int gg = 0; gg < 16; ++gg) {
        G1_BODY(2 * gg, 0, AC, AN);
        G1_BODY(2 * gg + 1, 1, AN, AC);
    }
#undef G1_BODY

    // reduce partial logits over the 16 u-lanes
#pragma unroll
    for (int m = 1; m < 16; m <<= 1) {
#pragma unroll
        for (int a = 0; a < 3; ++a)
#pragma unroll
            for (int i = 0; i < 4; ++i)
#pragma unroll
                for (int q = 0; q < 4; ++q)
                    plog[a][i][q] += __shfl_xor(plog[a][i][q], m);
    }
    if (lr == 0) {
#pragma unroll
        for (int a = 0; a < 3; ++a)
#pragma unroll
            for (int i = 0; i < 4; ++i)
#pragma unroll
            for (int q = 0; q < 4; ++q)
                red[wu][wm][i][lg][q][a] = plog[a][i][q];
    }
    __syncthreads();
    if (tid < 128) {
        const int r = tid;
        const int wmr = r >> 6, ir = (r >> 4) & 3, lgr = (r >> 2) & 3, qr = r & 3;
        float l0 = b2v[0], l1 = b2v[1], l2 = b2v[2];
#pragma unroll
        for (int u = 0; u < 4; ++u) {
            l0 += red[u][wmr][ir][lgr][qr][0];
            l1 += red[u][wmr][ir][lgr][qr][1];
            l2 += red[u][wmr][ir][lgr][qr][2];
        }
        const float mx = fmaxf(l0, fmaxf(l1, l2));
        const float e0 = __expf(l0 - mx), e1 = __expf(l1 - mx), e2 = __expf(l2 - mx);
        const float inv = 1.f / (e0 + e1 + e2);
        *(float4*)(actions + (size_t)(m0 + r) * 4) = make_float4(e0 * inv, e1 * inv, e2 * inv, 0.f);
    }
}

// ---------------- fused kernel: scan (blocks 0..31) + prep transpose --------
union SPMem {
    float tile[64][65];
    struct {
        float4 actbuf[3][256];
        float  sums[2][256][16];
    } s;
};

__device__ __forceinline__ void rs_chunk(const float4* __restrict__ pb,
                                         float* __restrict__ so,
                                         float& rs, int lane)
{
    for (int w = 0; w < 32; ++w) {
        const int rtop = 255 - w * 8;
        const float4 e0 = pb[rtop],     e1 = pb[rtop - 1];
        const float4 e2 = pb[rtop - 2], e3 = pb[rtop - 3];
        const float4 e4 = pb[rtop - 4], e5 = pb[rtop - 5];
        const float4 e6 = pb[rtop - 6], e7 = pb[rtop - 7];
#define RS_STEP(E, k) do {                                                    \
        const float rsp = dpp_shr1_z(rs);                                     \
        const float s = (E).y * rsp;                                          \
        if (lane < 16) so[(rtop - (k)) * 16 + lane] = s;                      \
        rs = fmaf((E).x + (E).z, rs, s);                                      \
    } while (0)
        RS_STEP(e0, 0); RS_STEP(e1, 1); RS_STEP(e2, 2); RS_STEP(e3, 3);
        RS_STEP(e4, 4); RS_STEP(e5, 5); RS_STEP(e6, 6); RS_STEP(e7, 7);
#undef RS_STEP
    }
}

__device__ __forceinline__ void t_chunk(const float4* __restrict__ lb,
                                        const float* __restrict__ sp,
                                        float& T, bf16* __restrict__ obp,
                                        int tbase0, int w15)
{
    for (int w = 0; w < 32; ++w) {
        const int rtop = 255 - w * 8;
        const int tglob = tbase0 + rtop - 7;
        const float4 av0 = lb[rtop],     av1 = lb[rtop - 1];
        const float4 av2 = lb[rtop - 2], av3 = lb[rtop - 3];
        const float4 av4 = lb[rtop - 4], av5 = lb[rtop - 5];
        const float4 av6 = lb[rtop - 6], av7 = lb[rtop - 7];
        const float su0 = sp[rtop * 16],       su1 = sp[(rtop - 1) * 16];
        const float su2 = sp[(rtop - 2) * 16], su3 = sp[(rtop - 3) * 16];
        const float su4 = sp[(rtop - 4) * 16], su5 = sp[(rtop - 5) * 16];
        const float su6 = sp[(rtop - 6) * 16], su7 = sp[(rtop - 7) * 16];
        bf16x8 fr;
#define T_STEP(Av, Su, fi) do {                                               \
        const float a0 = (Av).x, a1 = (Av).y, a2 = (Av).z;                    \
        fr[fi] = (bf16)((a0 + a1) * T);                                       \
        const float nT = dpp_shl1_z(T);                                       \
        const float contrib = w15 ? (Su) : a0 * nT;                           \
        T = fmaf(a2, T, contrib);                                             \
    } while (0)
        T_STEP(av0, su0, 7); T_STEP(av1, su1, 6);
        T_STEP(av2, su2, 5); T_STEP(av3, su3, 4);
        T_STEP(av4, su4, 3); T_STEP(av5, su5, 2);
        T_STEP(av6, su6, 1); T_STEP(av7, su7, 0);
#undef T_STEP
        *(bf16x8*)(obp + tglob) = fr;
    }
}

__global__ __launch_bounds__(320) void k_scan_prep(
    const float* __restrict__ actions, bf16* __restrict__ wsT,
    const float* __restrict__ seq, bf16* __restrict__ tHi)
{
    __shared__ SPMem sm;
    const int tid = threadIdx.x;
    if (blockIdx.x < 32) {
        const int b = blockIdx.x;
        const int wid = tid >> 6;
        const int lane = tid & 63;
        const float4* actb = (const float4*)actions + (size_t)b * S_LEN;

        float rs = (lane == 0) ? 1.f : 0.f;
        float T = (wid == 0 && lane == 15) ? 1.f : 0.f;
        const int w15 = ((lane & 15) == 15) ? 1 : 0;
        bf16* obp = wsT + ((size_t)b * NP + wid * 64 + lane) * S_LEN;

        if (wid < 4) {
            gload16(actb + 1792 + wid * 64 + lane, &sm.s.actbuf[0][wid * 64]);
            gload16(actb + 1536 + wid * 64 + lane, &sm.s.actbuf[1][wid * 64]);
            asm volatile("s_waitcnt vmcnt(0)" ::: "memory");
        }
        __syncthreads();
        if (wid == 4) rs_chunk(sm.s.actbuf[0], &sm.s.sums[0][0][0], rs, lane);
        __syncthreads();

        int bufT = 0, bufP = 1, bufL = 2;
        for (int c = 0; c < 8; ++c) {
            if (wid < 4) {
                if (c < 6)
                    gload16(actb + (1280 - c * 256) + wid * 64 + lane,
                            &sm.s.actbuf[bufL][wid * 64]);
                t_chunk(sm.s.actbuf[bufT],
                        &sm.s.sums[c & 1][0][wid * 4 + (lane >> 4)],
                        T, obp, 1792 - c * 256, w15);
                asm volatile("s_waitcnt vmcnt(0)" ::: "memory");
            } else {
                if (c < 7)
                    rs_chunk(sm.s.actbuf[bufP], &sm.s.sums[(c + 1) & 1][0][0], rs, lane);
            }
            __syncthreads();
            const int t = bufT; bufT = bufP; bufP = bufL; bufL = t;
        }
        return;
    }
    // ---- prep transpose path ----
    const int bid = blockIdx.x - 32;
    const int b = bid >> 8;
    const int r = bid & 255;
    const int s0 = (r & 31) << 6;
    const int e0 = (r >> 5) << 6;
    const int tx = tid & 15, ty = (tid & 255) >> 4;
    const float* src = seq + ((size_t)b * S_LEN + s0) * NE + e0;
    if (tid < 256) {
#pragma unroll
        for (int i = 0; i < 4; ++i) {
            const int row = ty + i * 16;
            const float4 v = *(const float4*)(src + (size_t)row * NE + tx * 4);
            sm.tile[row][tx * 4 + 0] = v.x; sm.tile[row][tx * 4 + 1] = v.y;
            sm.tile[row][tx * 4 + 2] = v.z; sm.tile[row][tx * 4 + 3] = v.w;
        }
    }
    __syncthreads();
    if (tid < 256) {
        const int sx = tid & 7, ey = tid >> 3;
#pragma unroll
        for (int jj = 0; jj < 2; ++jj) {
            const int er = ey + jj * 32;
            bf16x8 oh;
#pragma unroll
            for (int q = 0; q < 8; ++q) oh[q] = (bf16)sm.tile[sx * 8 + q][er];
            *(bf16x8*)(tHi + ((size_t)b * NE + e0 + er) * S_LEN + s0 + sx * 8) = oh;
        }
    }
}

// ---------------- kernel 3: GEMM2 partials (2-way k-split, LDS-staged) ------
__global__ __launch_bounds__(256, 2) void k_gemm2(
    const bf16* __restrict__ wsT, const bf16* __restrict__ seqtH,
    float* __restrict__ part)
{
    __shared__ __align__(16) bf16 AL[2][4096];
    __shared__ __align__(16) bf16 BL[2][4096];
    const int tid = threadIdx.x;
    const int wid = tid >> 6;
    const int lane = tid & 63;
    const int lr = lane & 15, lg = lane >> 4;
    const int bid = blockIdx.x;
    const int b = bid >> 4;
    const int sub = bid & 15;
    const int kc = sub >> 3;
    const int p0 = ((sub >> 2) & 1) << 7;
    const int e0 = (sub & 3) << 7;

    const bf16* Abase = wsT + ((size_t)b * NP + p0) * S_LEN + kc * 1024;
    const bf16* Bbase = seqtH + ((size_t)b * NE + e0) * S_LEN + kc * 1024;
    const int lroff = lr * 64 + (lg ^ ((lr >> 1) & 3)) * 16;

    f32x4 acc[2][8];
#pragma unroll
    for (int i = 0; i < 2; ++i)
#pragma unroll
        for (int j = 0; j < 8; ++j) acc[i][j] = (f32x4)(0.f);

    stage_tile(Abase, S_LEN, AL[0], tid);
    stage_tile(Bbase, S_LEN, BL[0], tid);

#define G2_BODY(kt, buf) do {                                                 \
        __syncthreads();                                                      \
        bf16x8 af[2], bfv[8];                                                 \
        _Pragma("unroll") for (int i = 0; i < 2; ++i)                         \
            af[i] = *(const bf16x8*)((const char*)AL[buf]                     \
                     + (wid * 32 + i * 16) * 64 + lroff);                     \
        _Pragma("unroll") for (int j = 0; j < 8; ++j)                         \
            bfv[j] = *(const bf16x8*)((const char*)BL[buf] + j * 1024 + lroff);\
        __syncthreads();                                                      \
        if ((kt) < 31) {                                                      \
            stage_tile(Abase + ((kt) + 1) * 32, S_LEN, AL[(buf) ^ 1], tid);   \
            stage_tile(Bbase + ((kt) + 1) * 32, S_LEN, BL[(buf) ^ 1], tid);   \
        }                                                                     \
        _Pragma("unroll") for (int j = 0; j < 8; ++j) {                       \
            acc[0][j] = __builtin_amdgcn_mfma_f32_16x16x32_bf16(af[0], bfv[j], acc[0][j], 0, 0, 0); \
            acc[1][j] = __builtin_amdgcn_mfma_f32_16x16x32_bf16(af[1], bfv[j], acc[1][j], 0, 0, 0); \
        }                                                                     \
    } while (0)

    for (int kk = 0; kk < 16; ++kk) {
        G2_BODY(2 * kk, 0);
        G2_BODY(2 * kk + 1, 1);
    }
#undef G2_BODY

    float* obp = part + (((size_t)kc * NB + b) * NP + p0 + wid * 32) * NE + e0;
#pragma unroll
    for (int i = 0; i < 2; ++i)
#pragma unroll
        for (int j = 0; j < 8; ++j)
#pragma unroll
            for (int q = 0; q < 4; ++q)
                obp[(size_t)(i * 16 + lg * 4 + q) * NE + j * 16 + lr] = acc[i][j][q];
}

// ---------------- kernel 4: reduce the 2 partials ---------------------------
__global__ __launch_bounds__(256) void k_gred(
    const float* __restrict__ part, float* __restrict__ outp)
{
    const size_t i = ((size_t)blockIdx.x * 256 + threadIdx.x) * 4;
    const float4 p0 = *(const float4*)(part + i);
    const float4 p1 = *(const float4*)(part + ((size_t)NB * NP * NE) + i);
    *(float4*)(outp + i) = make_float4(p0.x + p1.x, p0.y + p1.y,
                                       p0.z + p1.z, p0.w + p1.w);
}

// ---------------- launch ----------------------------------------------------
extern "C" void kernel_launch(void* const* d_in, const int* in_sizes, int n_in,
                              void* d_out, int out_size, void* d_ws, size_t ws_size,
                              hipStream_t stream) {
    (void)in_sizes; (void)n_in; (void)out_size; (void)ws_size;
    const float* seq = (const float*)d_in[0];
    const float* w1  = (const float*)d_in[1];
    const float* b1  = (const float*)d_in[2];
    const float* w2  = (const float*)d_in[3];
    const float* b2  = (const float*)d_in[4];
    float* outp = (float*)d_out;

    char* ws = (char*)d_ws;
    bf16*  seqtH   = (bf16*)(ws);                        // 64 MB [b][e][s]
    bf16*  wsT     = (bf16*)(ws + (64ull << 20));        // 32 MB [b][p][t]
    float* actions = (float*)(ws + (96ull << 20));       // 1 MB  [b*S][4]
    bf16*  w1H     = (bf16*)(ws + (97ull << 20));        // 512 KB
    bf16*  w1L     = (bf16*)(ws + (97ull << 20) + (512u << 10)); // 512 KB
    float* part    = (float*)(ws + (98ull << 20));       // 32 MB [2][b][p][e]

    hipLaunchKernelGGL(k_wconv, dim3(256),  dim3(256), 0, stream, w1, w1H, w1L);
    hipLaunchKernelGGL(k_gemm1, dim3(512),  dim3(512), 0, stream,
                       seq, w1H, w1L, b1, w2, b2, actions);
    hipLaunchKernelGGL(k_scan_prep, dim3(32 + 8192), dim3(320), 0, stream,
                       actions, wsT, seq, seqtH);
    hipLaunchKernelGGL(k_gemm2, dim3(512),  dim3(256), 0, stream, wsT, seqtH, part);
    hipLaunchKernelGGL(k_gred,  dim3(4096), dim3(256), 0, stream, part, outp);
}

// Round 9
// 341.313 us; speedup vs baseline: 1.2549x; 1.1138x over previous
//
#include <hip/hip_runtime.h>
#include <stdint.h>

#define S_LEN 2048
#define NB 32
#define NE 512
#define NU 512
#define NP 256

typedef __bf16 bf16;
typedef __bf16 bf16x8 __attribute__((ext_vector_type(8)));
typedef __bf16 bf16x4 __attribute__((ext_vector_type(4)));
typedef float f32x4 __attribute__((ext_vector_type(4)));
typedef float f32x8 __attribute__((ext_vector_type(8)));

__device__ __forceinline__ void gload16(const void* g, void* l) {
    __builtin_amdgcn_global_load_lds(
        (__attribute__((address_space(1))) void*)g,
        (__attribute__((address_space(3))) void*)l, 16, 0, 0);
}

// DPP helpers (HW-verified rounds 4-6)
__device__ __forceinline__ float dpp_shr1_z(float x) {
    return __builtin_bit_cast(float, __builtin_amdgcn_update_dpp(
        0, __builtin_bit_cast(int, x), 0x111, 0xF, 0xF, true));
}
__device__ __forceinline__ float dpp_shl1_z(float x) {
    return __builtin_bit_cast(float, __builtin_amdgcn_update_dpp(
        0, __builtin_bit_cast(int, x), 0x101, 0xF, 0xF, true));
}

// Stage a 128-row x 32-col bf16 tile (row stride SR) into 8KB LDS (256 thr);
// self-inverse k-quad permutation q = (c&3) ^ ((row>>1)&3).
__device__ __forceinline__ void stage_tile(const bf16* __restrict__ src, int SR,
                                           bf16* lds, int tid) {
#pragma unroll
    for (int rnd = 0; rnd < 2; ++rnd) {
        const int c = rnd * 256 + tid;
        const int row = c >> 2;
        const int q = (c & 3) ^ ((c >> 3) & 3);
        gload16(src + (size_t)row * SR + q * 8, lds + c * 8);
    }
}

// ---------------- kernel 0b: w1 fp32 -> bf16 hi/lo --------------------------
__global__ __launch_bounds__(256) void k_wconv(
    const float* __restrict__ w1, bf16* __restrict__ wHi, bf16* __restrict__ wLo)
{
    const int i = (blockIdx.x * 256 + threadIdx.x) * 4;
    const float4 v = *(const float4*)(w1 + i);
    const float vv[4] = {v.x, v.y, v.z, v.w};
    bf16x4 oh, ol;
#pragma unroll
    for (int q = 0; q < 4; ++q) {
        const bf16 hb = (bf16)vv[q];
        oh[q] = hb;
        ol[q] = (bf16)(vv[q] - (float)hb);
    }
    *(bf16x4*)(wHi + i) = oh;
    *(bf16x4*)(wLo + i) = ol;
}

// ---------------- kernel 1: GEMM1 + silu + logits + softmax -----------------
// 256 threads = 4 waves (wm 0..1 x wu 0..1). Wave = 64 rows (4 m-frags) x
// 64 u (4 j-frags): 8 ds_read_b128 per g for 48 MFMA (half of r6's 16).
// Block = 128 rows x 128-u panel, 4 panels. A = seq fp32 per-lane (hi/lo in
// regs); B = w1 hi/lo LDS dbuf. launch_bounds(256,2): VGPR cap 256, no spill.
__global__ __launch_bounds__(256, 2) void k_gemm1(
    const float* __restrict__ seq,
    const bf16* __restrict__ w1H, const bf16* __restrict__ w1L,
    const float* __restrict__ b1v, const float* __restrict__ w2,
    const float* __restrict__ b2v, float* __restrict__ actions)
{
    __shared__ __align__(16) bf16 BhL[2][4096];
    __shared__ __align__(16) bf16 BlL[2][4096];
    __shared__ float red[2][2][4][4][4][3];   // [wu][wm][i][lg][q][a] 4.6KB
    const int tid = threadIdx.x;
    const int wid = tid >> 6;
    const int wm = wid >> 1, wu = wid & 1;
    const int lane = tid & 63;
    const int lr = lane & 15, lg = lane >> 4;
    const int m0 = blockIdx.x << 7;

    const float* ar[4];
#pragma unroll
    for (int i = 0; i < 4; ++i)
        ar[i] = seq + (size_t)(m0 + wm * 64 + i * 16 + lr) * NE + lg * 8;
    const int lbase = (wu * 64 + lr) * 64 + (lg ^ ((lr >> 1) & 3)) * 16;

    float plog[3][4][4];
#pragma unroll
    for (int a = 0; a < 3; ++a)
#pragma unroll
        for (int i = 0; i < 4; ++i)
#pragma unroll
            for (int q = 0; q < 4; ++q) plog[a][i][q] = 0.f;

    f32x4 acc[4][4];
    stage_tile(w1H, NE, BhL[0], tid);
    stage_tile(w1L, NE, BlL[0], tid);
    f32x8 AC[4], AN[4];
#pragma unroll
    for (int i = 0; i < 4; ++i) AC[i] = *(const f32x8*)(ar[i]);

#define G1_BODY(g, buf, Ac, An) do {                                          \
        __syncthreads();                                                      \
        if (((g) & 15) == 0) {                                                \
            _Pragma("unroll") for (int i = 0; i < 4; ++i)                     \
            _Pragma("unroll") for (int j = 0; j < 4; ++j)                     \
                acc[i][j] = (f32x4)(0.f);                                     \
        }                                                                     \
        bf16x8 bh[4], bl[4];                                                  \
        _Pragma("unroll") for (int j = 0; j < 4; ++j) {                       \
            bh[j] = *(const bf16x8*)((const char*)BhL[buf] + j * 1024 + lbase);\
            bl[j] = *(const bf16x8*)((const char*)BlL[buf] + j * 1024 + lbase);\
        }                                                                     \
        __syncthreads();                                                      \
        if ((g) < 63) {                                                       \
            const int gn = (g) + 1;                                           \
            const int u0n = (gn >> 4) << 7;                                   \
            const int k0n = (gn & 15) << 5;                                   \
            stage_tile(w1H + (size_t)u0n * NE + k0n, NE, BhL[(buf) ^ 1], tid);\
            stage_tile(w1L + (size_t)u0n * NE + k0n, NE, BlL[(buf) ^ 1], tid);\
            _Pragma("unroll") for (int i = 0; i < 4; ++i)                     \
                An[i] = *(const f32x8*)(ar[i] + k0n);                         \
        }                                                                     \
        bf16x8 Ah[4], Al[4];                                                  \
        _Pragma("unroll") for (int i = 0; i < 4; ++i)                         \
        _Pragma("unroll") for (int e = 0; e < 8; ++e) {                       \
            const bf16 hb = (bf16)Ac[i][e];                                   \
            Ah[i][e] = hb; Al[i][e] = (bf16)(Ac[i][e] - (float)hb);           \
        }                                                                     \
        _Pragma("unroll") for (int j = 0; j < 4; ++j)                         \
        _Pragma("unroll") for (int i = 0; i < 4; ++i) {                       \
            acc[i][j] = __builtin_amdgcn_mfma_f32_16x16x32_bf16(Ah[i], bh[j], acc[i][j], 0, 0, 0); \
            acc[i][j] = __builtin_amdgcn_mfma_f32_16x16x32_bf16(Ah[i], bl[j], acc[i][j], 0, 0, 0); \
            acc[i][j] = __builtin_amdgcn_mfma_f32_16x16x32_bf16(Al[i], bh[j], acc[i][j], 0, 0, 0); \
        }                                                                     \
        if (((g) & 15) == 15) {                                               \
            const int p = (g) >> 4;                                           \
            _Pragma("unroll") for (int j = 0; j < 4; ++j) {                   \
                const int col = p * 128 + wu * 64 + j * 16 + lr;              \
                const float b1c = b1v[col];                                   \
                const float w20 = w2[col], w21 = w2[NU + col], w22 = w2[2 * NU + col]; \
                _Pragma("unroll") for (int i = 0; i < 4; ++i)                 \
                _Pragma("unroll") for (int q = 0; q < 4; ++q) {               \
                    const float x = acc[i][j][q] + b1c;                       \
                    const float hg = x / (1.f + __expf(-x));                  \
                    plog[0][i][q] = fmaf(hg, w20, plog[0][i][q]);             \
                    plog[1][i][q] = fmaf(hg, w21, plog[1][i][q]);             \
                    plog[2][i][q] = fmaf(hg, w22, plog[2][i][q]);             \
                }                                                             \
            }                                                                 \
        }                                                                     \
    } while (0)

    for (int gg = 0; gg < 32; ++gg) {
        G1_BODY(2 * gg, 0, AC, AN);
        G1_BODY(2 * gg + 1, 1, AN, AC);
    }
#undef G1_BODY

    // reduce partial logits over the 16 u-lanes (lr bits)
#pragma unroll
    for (int m = 1; m < 16; m <<= 1) {
#pragma unroll
        for (int a = 0; a < 3; ++a)
#pragma unroll
            for (int i = 0; i < 4; ++i)
#pragma unroll
                for (int q = 0; q < 4; ++q)
                    plog[a][i][q] += __shfl_xor(plog[a][i][q], m);
    }
    if (lr == 0) {
#pragma unroll
        for (int a = 0; a < 3; ++a)
#pragma unroll
            for (int i = 0; i < 4; ++i)
#pragma unroll
                for (int q = 0; q < 4; ++q)
                    red[wu][wm][i][lg][q][a] = plog[a][i][q];
    }
    __syncthreads();
    if (tid < 128) {
        const int r = tid;
        const int wmr = r >> 6, ir = (r >> 4) & 3, lgr = (r >> 2) & 3, qr = r & 3;
        float l0 = b2v[0] + red[0][wmr][ir][lgr][qr][0] + red[1][wmr][ir][lgr][qr][0];
        float l1 = b2v[1] + red[0][wmr][ir][lgr][qr][1] + red[1][wmr][ir][lgr][qr][1];
        float l2 = b2v[2] + red[0][wmr][ir][lgr][qr][2] + red[1][wmr][ir][lgr][qr][2];
        const float mx = fmaxf(l0, fmaxf(l1, l2));
        const float e0 = __expf(l0 - mx), e1 = __expf(l1 - mx), e2 = __expf(l2 - mx);
        const float inv = 1.f / (e0 + e1 + e2);
        *(float4*)(actions + (size_t)(m0 + r) * 4) = make_float4(e0 * inv, e1 * inv, e2 * inv, 0.f);
    }
}

// ---------------- fused kernel: scan (blocks 0..31) + prep transpose --------
union SPMem {
    float tile[64][65];
    struct {
        float4 actbuf[3][256];
        float  sums[2][256][16];
    } s;
};

__device__ __forceinline__ void rs_chunk(const float4* __restrict__ pb,
                                         float* __restrict__ so,
                                         float& rs, int lane)
{
    for (int w = 0; w < 32; ++w) {
        const int rtop = 255 - w * 8;
        const float4 e0 = pb[rtop],     e1 = pb[rtop - 1];
        const float4 e2 = pb[rtop - 2], e3 = pb[rtop - 3];
        const float4 e4 = pb[rtop - 4], e5 = pb[rtop - 5];
        const float4 e6 = pb[rtop - 6], e7 = pb[rtop - 7];
#define RS_STEP(E, k) do {                                                    \
        const float rsp = dpp_shr1_z(rs);                                     \
        const float s = (E).y * rsp;                                          \
        if (lane < 16) so[(rtop - (k)) * 16 + lane] = s;                      \
        rs = fmaf((E).x + (E).z, rs, s);                                      \
    } while (0)
        RS_STEP(e0, 0); RS_STEP(e1, 1); RS_STEP(e2, 2); RS_STEP(e3, 3);
        RS_STEP(e4, 4); RS_STEP(e5, 5); RS_STEP(e6, 6); RS_STEP(e7, 7);
#undef RS_STEP
    }
}

__device__ __forceinline__ void t_chunk(const float4* __restrict__ lb,
                                        const float* __restrict__ sp,
                                        float& T, bf16* __restrict__ obp,
                                        int tbase0, int w15)
{
    for (int w = 0; w < 32; ++w) {
        const int rtop = 255 - w * 8;
        const int tglob = tbase0 + rtop - 7;
        const float4 av0 = lb[rtop],     av1 = lb[rtop - 1];
        const float4 av2 = lb[rtop - 2], av3 = lb[rtop - 3];
        const float4 av4 = lb[rtop - 4], av5 = lb[rtop - 5];
        const float4 av6 = lb[rtop - 6], av7 = lb[rtop - 7];
        const float su0 = sp[rtop * 16],       su1 = sp[(rtop - 1) * 16];
        const float su2 = sp[(rtop - 2) * 16], su3 = sp[(rtop - 3) * 16];
        const float su4 = sp[(rtop - 4) * 16], su5 = sp[(rtop - 5) * 16];
        const float su6 = sp[(rtop - 6) * 16], su7 = sp[(rtop - 7) * 16];
        bf16x8 fr;
#define T_STEP(Av, Su, fi) do {                                               \
        const float a0 = (Av).x, a1 = (Av).y, a2 = (Av).z;                    \
        fr[fi] = (bf16)((a0 + a1) * T);                                       \
        const float nT = dpp_shl1_z(T);                                       \
        const float contrib = w15 ? (Su) : a0 * nT;                           \
        T = fmaf(a2, T, contrib);                                             \
    } while (0)
        T_STEP(av0, su0, 7); T_STEP(av1, su1, 6);
        T_STEP(av2, su2, 5); T_STEP(av3, su3, 4);
        T_STEP(av4, su4, 3); T_STEP(av5, su5, 2);
        T_STEP(av6, su6, 1); T_STEP(av7, su7, 0);
#undef T_STEP
        *(bf16x8*)(obp + tglob) = fr;
    }
}

__global__ __launch_bounds__(320) void k_scan_prep(
    const float* __restrict__ actions, bf16* __restrict__ wsT,
    const float* __restrict__ seq, bf16* __restrict__ tHi)
{
    __shared__ SPMem sm;
    const int tid = threadIdx.x;
    if (blockIdx.x < 32) {
        const int b = blockIdx.x;
        const int wid = tid >> 6;
        const int lane = tid & 63;
        const float4* actb = (const float4*)actions + (size_t)b * S_LEN;

        float rs = (lane == 0) ? 1.f : 0.f;
        float T = (wid == 0 && lane == 15) ? 1.f : 0.f;
        const int w15 = ((lane & 15) == 15) ? 1 : 0;
        bf16* obp = wsT + ((size_t)b * NP + wid * 64 + lane) * S_LEN;

        if (wid < 4) {
            gload16(actb + 1792 + wid * 64 + lane, &sm.s.actbuf[0][wid * 64]);
            gload16(actb + 1536 + wid * 64 + lane, &sm.s.actbuf[1][wid * 64]);
            asm volatile("s_waitcnt vmcnt(0)" ::: "memory");
        }
        __syncthreads();
        if (wid == 4) rs_chunk(sm.s.actbuf[0], &sm.s.sums[0][0][0], rs, lane);
        __syncthreads();

        int bufT = 0, bufP = 1, bufL = 2;
        for (int c = 0; c < 8; ++c) {
            if (wid < 4) {
                if (c < 6)
                    gload16(actb + (1280 - c * 256) + wid * 64 + lane,
                            &sm.s.actbuf[bufL][wid * 64]);
                t_chunk(sm.s.actbuf[bufT],
                        &sm.s.sums[c & 1][0][wid * 4 + (lane >> 4)],
                        T, obp, 1792 - c * 256, w15);
                asm volatile("s_waitcnt vmcnt(0)" ::: "memory");
            } else {
                if (c < 7)
                    rs_chunk(sm.s.actbuf[bufP], &sm.s.sums[(c + 1) & 1][0][0], rs, lane);
            }
            __syncthreads();
            const int t = bufT; bufT = bufP; bufP = bufL; bufL = t;
        }
        return;
    }
    // ---- prep transpose path ----
    const int bid = blockIdx.x - 32;
    const int b = bid >> 8;
    const int r = bid & 255;
    const int s0 = (r & 31) << 6;
    const int e0 = (r >> 5) << 6;
    const int tx = tid & 15, ty = (tid & 255) >> 4;
    const float* src = seq + ((size_t)b * S_LEN + s0) * NE + e0;
    if (tid < 256) {
#pragma unroll
        for (int i = 0; i < 4; ++i) {
            const int row = ty + i * 16;
            const float4 v = *(const float4*)(src + (size_t)row * NE + tx * 4);
            sm.tile[row][tx * 4 + 0] = v.x; sm.tile[row][tx * 4 + 1] = v.y;
            sm.tile[row][tx * 4 + 2] = v.z; sm.tile[row][tx * 4 + 3] = v.w;
        }
    }
    __syncthreads();
    if (tid < 256) {
        const int sx = tid & 7, ey = tid >> 3;
#pragma unroll
        for (int jj = 0; jj < 2; ++jj) {
            const int er = ey + jj * 32;
            bf16x8 oh;
#pragma unroll
            for (int q = 0; q < 8; ++q) oh[q] = (bf16)sm.tile[sx * 8 + q][er];
            *(bf16x8*)(tHi + ((size_t)b * NE + e0 + er) * S_LEN + s0 + sx * 8) = oh;
        }
    }
}

// ---------------- kernel 3: GEMM2 partials (2-way k-split, LDS-staged) ------
__global__ __launch_bounds__(256, 2) void k_gemm2(
    const bf16* __restrict__ wsT, const bf16* __restrict__ seqtH,
    float* __restrict__ part)
{
    __shared__ __align__(16) bf16 AL[2][4096];
    __shared__ __align__(16) bf16 BL[2][4096];
    const int tid = threadIdx.x;
    const int wid = tid >> 6;
    const int lane = tid & 63;
    const int lr = lane & 15, lg = lane >> 4;
    const int bid = blockIdx.x;
    const int b = bid >> 4;
    const int sub = bid & 15;
    const int kc = sub >> 3;
    const int p0 = ((sub >> 2) & 1) << 7;
    const int e0 = (sub & 3) << 7;

    const bf16* Abase = wsT + ((size_t)b * NP + p0) * S_LEN + kc * 1024;
    const bf16* Bbase = seqtH + ((size_t)b * NE + e0) * S_LEN + kc * 1024;
    const int lroff = lr * 64 + (lg ^ ((lr >> 1) & 3)) * 16;

    f32x4 acc[2][8];
#pragma unroll
    for (int i = 0; i < 2; ++i)
#pragma unroll
        for (int j = 0; j < 8; ++j) acc[i][j] = (f32x4)(0.f);

    stage_tile(Abase, S_LEN, AL[0], tid);
    stage_tile(Bbase, S_LEN, BL[0], tid);

#define G2_BODY(kt, buf) do {                                                 \
        __syncthreads();                                                      \
        bf16x8 af[2], bfv[8];                                                 \
        _Pragma("unroll") for (int i = 0; i < 2; ++i)                         \
            af[i] = *(const bf16x8*)((const char*)AL[buf]                     \
                     + (wid * 32 + i * 16) * 64 + lroff);                     \
        _Pragma("unroll") for (int j = 0; j < 8; ++j)                         \
            bfv[j] = *(const bf16x8*)((const char*)BL[buf] + j * 1024 + lroff);\
        __syncthreads();                                                      \
        if ((kt) < 31) {                                                      \
            stage_tile(Abase + ((kt) + 1) * 32, S_LEN, AL[(buf) ^ 1], tid);   \
            stage_tile(Bbase + ((kt) + 1) * 32, S_LEN, BL[(buf) ^ 1], tid);   \
        }                                                                     \
        _Pragma("unroll") for (int j = 0; j < 8; ++j) {                       \
            acc[0][j] = __builtin_amdgcn_mfma_f32_16x16x32_bf16(af[0], bfv[j], acc[0][j], 0, 0, 0); \
            acc[1][j] = __builtin_amdgcn_mfma_f32_16x16x32_bf16(af[1], bfv[j], acc[1][j], 0, 0, 0); \
        }                                                                     \
    } while (0)

    for (int kk = 0; kk < 16; ++kk) {
        G2_BODY(2 * kk, 0);
        G2_BODY(2 * kk + 1, 1);
    }
#undef G2_BODY

    float* obp = part + (((size_t)kc * NB + b) * NP + p0 + wid * 32) * NE + e0;
#pragma unroll
    for (int i = 0; i < 2; ++i)
#pragma unroll
        for (int j = 0; j < 8; ++j)
#pragma unroll
            for (int q = 0; q < 4; ++q)
                obp[(size_t)(i * 16 + lg * 4 + q) * NE + j * 16 + lr] = acc[i][j][q];
}

// ---------------- kernel 4: reduce the 2 partials ---------------------------
__global__ __launch_bounds__(256) void k_gred(
    const float* __restrict__ part, float* __restrict__ outp)
{
    const size_t i = ((size_t)blockIdx.x * 256 + threadIdx.x) * 4;
    const float4 p0 = *(const float4*)(part + i);
    const float4 p1 = *(const float4*)(part + ((size_t)NB * NP * NE) + i);
    *(float4*)(outp + i) = make_float4(p0.x + p1.x, p0.y + p1.y,
                                       p0.z + p1.z, p0.w + p1.w);
}

// ---------------- launch ----------------------------------------------------
extern "C" void kernel_launch(void* const* d_in, const int* in_sizes, int n_in,
                              void* d_out, int out_size, void* d_ws, size_t ws_size,
                              hipStream_t stream) {
    (void)in_sizes; (void)n_in; (void)out_size; (void)ws_size;
    const float* seq = (const float*)d_in[0];
    const float* w1  = (const float*)d_in[1];
    const float* b1  = (const float*)d_in[2];
    const float* w2  = (const float*)d_in[3];
    const float* b2  = (const float*)d_in[4];
    float* outp = (float*)d_out;

    char* ws = (char*)d_ws;
    bf16*  seqtH   = (bf16*)(ws);                        // 64 MB [b][e][s]
    bf16*  wsT     = (bf16*)(ws + (64ull << 20));        // 32 MB [b][p][t]
    float* actions = (float*)(ws + (96ull << 20));       // 1 MB  [b*S][4]
    bf16*  w1H     = (bf16*)(ws + (97ull << 20));        // 512 KB
    bf16*  w1L     = (bf16*)(ws + (97ull << 20) + (512u << 10)); // 512 KB
    float* part    = (float*)(ws + (98ull << 20));       // 32 MB [2][b][p][e]

    hipLaunchKernelGGL(k_wconv, dim3(256),  dim3(256), 0, stream, w1, w1H, w1L);
    hipLaunchKernelGGL(k_gemm1, dim3(512),  dim3(256), 0, stream,
                       seq, w1H, w1L, b1, w2, b2, actions);
    hipLaunchKernelGGL(k_scan_prep, dim3(32 + 8192), dim3(320), 0, stream,
                       actions, wsT, seq, seqtH);
    hipLaunchKernelGGL(k_gemm2, dim3(512),  dim3(256), 0, stream, wsT, seqtH, part);
    hipLaunchKernelGGL(k_gred,  dim3(4096), dim3(256), 0, stream, part, outp);
}

// Round 10
// 339.026 us; speedup vs baseline: 1.2634x; 1.0067x over previous
//
#include <hip/hip_runtime.h>
#include <stdint.h>

#define S_LEN 2048
#define NB 32
#define NE 512
#define NU 512
#define NP 256

typedef __bf16 bf16;
typedef __bf16 bf16x8 __attribute__((ext_vector_type(8)));
typedef __bf16 bf16x4 __attribute__((ext_vector_type(4)));
typedef float f32x4 __attribute__((ext_vector_type(4)));
typedef float f32x8 __attribute__((ext_vector_type(8)));

__device__ __forceinline__ void gload16(const void* g, void* l) {
    __builtin_amdgcn_global_load_lds(
        (__attribute__((address_space(1))) void*)g,
        (__attribute__((address_space(3))) void*)l, 16, 0, 0);
}

// DPP helpers (HW-verified rounds 4-6)
__device__ __forceinline__ float dpp_shr1_z(float x) {
    return __builtin_bit_cast(float, __builtin_amdgcn_update_dpp(
        0, __builtin_bit_cast(int, x), 0x111, 0xF, 0xF, true));
}
__device__ __forceinline__ float dpp_shl1_z(float x) {
    return __builtin_bit_cast(float, __builtin_amdgcn_update_dpp(
        0, __builtin_bit_cast(int, x), 0x101, 0xF, 0xF, true));
}

// Stage a 128-row x 32-col bf16 tile (row stride SR) into 8KB LDS (256 thr);
// self-inverse k-quad permutation q = (c&3) ^ ((row>>1)&3).
__device__ __forceinline__ void stage_tile(const bf16* __restrict__ src, int SR,
                                           bf16* lds, int tid) {
#pragma unroll
    for (int rnd = 0; rnd < 2; ++rnd) {
        const int c = rnd * 256 + tid;
        const int row = c >> 2;
        const int q = (c & 3) ^ ((c >> 3) & 3);
        gload16(src + (size_t)row * SR + q * 8, lds + c * 8);
    }
}

// ---------------- kernel 0b: w1 fp32 -> bf16 hi/lo --------------------------
__global__ __launch_bounds__(256) void k_wconv(
    const float* __restrict__ w1, bf16* __restrict__ wHi, bf16* __restrict__ wLo)
{
    const int i = (blockIdx.x * 256 + threadIdx.x) * 4;
    const float4 v = *(const float4*)(w1 + i);
    const float vv[4] = {v.x, v.y, v.z, v.w};
    bf16x4 oh, ol;
#pragma unroll
    for (int q = 0; q < 4; ++q) {
        const bf16 hb = (bf16)vv[q];
        oh[q] = hb;
        ol[q] = (bf16)(vv[q] - (float)hb);
    }
    *(bf16x4*)(wHi + i) = oh;
    *(bf16x4*)(wLo + i) = ol;
}

// ---------------- kernel 1: GEMM1 partial logits ----------------------------
// grid 2048 = 512 m-blocks x 4 u-quarters; XCD-co-located siblings:
//   xcd = bid&7, idx = bid>>3, m = xcd*64 + (idx>>2), uq = idx&3
// block: 256 thr, 4 waves (wm x wu), wave = 64 rows x 64 u, SINGLE k-pass
// (16 kt). plog only exists AFTER the loop -> no spill. Writes per-uq
// partial logits; k_actfin reduces.
__global__ __launch_bounds__(256, 2) void k_gemm1(
    const float* __restrict__ seq,
    const bf16* __restrict__ w1H, const bf16* __restrict__ w1L,
    const float* __restrict__ b1v, const float* __restrict__ w2,
    float* __restrict__ plogit)    // [row][uq] float4 (l0,l1,l2,0)
{
    __shared__ __align__(16) bf16 BhL[2][4096];
    __shared__ __align__(16) bf16 BlL[2][4096];
    __shared__ float red[2][128][3];
    const int tid = threadIdx.x;
    const int wid = tid >> 6;
    const int wm = wid >> 1, wu = wid & 1;
    const int lane = tid & 63;
    const int lr = lane & 15, lg = lane >> 4;

    const int bid = blockIdx.x;
    const int xcd = bid & 7;
    const int idx = bid >> 3;
    const int mblk = xcd * 64 + (idx >> 2);
    const int uq = idx & 3;
    const int m0 = mblk << 7;
    const int u0 = uq << 7;

    const float* ar[4];
#pragma unroll
    for (int i = 0; i < 4; ++i)
        ar[i] = seq + (size_t)(m0 + wm * 64 + i * 16 + lr) * NE + lg * 8;
    const int lbase = (wu * 64 + lr) * 64 + (lg ^ ((lr >> 1) & 3)) * 16;
    const bf16* bH = w1H + (size_t)u0 * NE;
    const bf16* bL = w1L + (size_t)u0 * NE;

    f32x4 acc[4][4];
#pragma unroll
    for (int i = 0; i < 4; ++i)
#pragma unroll
        for (int j = 0; j < 4; ++j) acc[i][j] = (f32x4)(0.f);

    stage_tile(bH, NE, BhL[0], tid);
    stage_tile(bL, NE, BlL[0], tid);
    f32x8 AC[4], AN[4];
#pragma unroll
    for (int i = 0; i < 4; ++i) AC[i] = *(const f32x8*)(ar[i]);

#define G1_BODY(kt, buf, Ac, An) do {                                         \
        __syncthreads();                                                      \
        bf16x8 bh[4], bl[4];                                                  \
        _Pragma("unroll") for (int j = 0; j < 4; ++j) {                       \
            bh[j] = *(const bf16x8*)((const char*)BhL[buf] + j * 1024 + lbase);\
            bl[j] = *(const bf16x8*)((const char*)BlL[buf] + j * 1024 + lbase);\
        }                                                                     \
        __syncthreads();                                                      \
        if ((kt) < 15) {                                                      \
            const int k0n = ((kt) + 1) << 5;                                  \
            stage_tile(bH + k0n, NE, BhL[(buf) ^ 1], tid);                    \
            stage_tile(bL + k0n, NE, BlL[(buf) ^ 1], tid);                    \
            _Pragma("unroll") for (int i = 0; i < 4; ++i)                     \
                An[i] = *(const f32x8*)(ar[i] + k0n);                         \
        }                                                                     \
        bf16x8 Ah[4], Al[4];                                                  \
        _Pragma("unroll") for (int i = 0; i < 4; ++i)                         \
        _Pragma("unroll") for (int e = 0; e < 8; ++e) {                       \
            const bf16 hb = (bf16)Ac[i][e];                                   \
            Ah[i][e] = hb; Al[i][e] = (bf16)(Ac[i][e] - (float)hb);           \
        }                                                                     \
        _Pragma("unroll") for (int j = 0; j < 4; ++j)                         \
        _Pragma("unroll") for (int i = 0; i < 4; ++i) {                       \
            acc[i][j] = __builtin_amdgcn_mfma_f32_16x16x32_bf16(Ah[i], bh[j], acc[i][j], 0, 0, 0); \
            acc[i][j] = __builtin_amdgcn_mfma_f32_16x16x32_bf16(Ah[i], bl[j], acc[i][j], 0, 0, 0); \
            acc[i][j] = __builtin_amdgcn_mfma_f32_16x16x32_bf16(Al[i], bh[j], acc[i][j], 0, 0, 0); \
        }                                                                     \
    } while (0)

    for (int kk = 0; kk < 8; ++kk) {
        G1_BODY(2 * kk, 0, AC, AN);
        G1_BODY(2 * kk + 1, 1, AN, AC);
    }
#undef G1_BODY

    // epilogue (once): silu + partial logits over this block's 128-u range
    float plog[3][4][4];
#pragma unroll
    for (int a = 0; a < 3; ++a)
#pragma unroll
        for (int i = 0; i < 4; ++i)
#pragma unroll
            for (int q = 0; q < 4; ++q) plog[a][i][q] = 0.f;
#pragma unroll
    for (int j = 0; j < 4; ++j) {
        const int col = u0 + wu * 64 + j * 16 + lr;
        const float b1c = b1v[col];
        const float w20 = w2[col], w21 = w2[NU + col], w22 = w2[2 * NU + col];
#pragma unroll
        for (int i = 0; i < 4; ++i)
#pragma unroll
            for (int q = 0; q < 4; ++q) {
                const float x = acc[i][j][q] + b1c;
                const float hg = x / (1.f + __expf(-x));
                plog[0][i][q] = fmaf(hg, w20, plog[0][i][q]);
                plog[1][i][q] = fmaf(hg, w21, plog[1][i][q]);
                plog[2][i][q] = fmaf(hg, w22, plog[2][i][q]);
            }
    }
#pragma unroll
    for (int m = 1; m < 16; m <<= 1) {
#pragma unroll
        for (int a = 0; a < 3; ++a)
#pragma unroll
            for (int i = 0; i < 4; ++i)
#pragma unroll
                for (int q = 0; q < 4; ++q)
                    plog[a][i][q] += __shfl_xor(plog[a][i][q], m);
    }
    if (lr == 0) {
#pragma unroll
        for (int i = 0; i < 4; ++i)
#pragma unroll
            for (int q = 0; q < 4; ++q) {
                const int rl = wm * 64 + i * 16 + lg * 4 + q;
                red[wu][rl][0] = plog[0][i][q];
                red[wu][rl][1] = plog[1][i][q];
                red[wu][rl][2] = plog[2][i][q];
            }
    }
    __syncthreads();
    if (tid < 128) {
        const float l0 = red[0][tid][0] + red[1][tid][0];
        const float l1 = red[0][tid][1] + red[1][tid][1];
        const float l2 = red[0][tid][2] + red[1][tid][2];
        *(float4*)(plogit + ((size_t)(m0 + tid) * 4 + (size_t)uq * (size_t)NB * S_LEN * 4)) =
            make_float4(l0, l1, l2, 0.f);
    }
}

// ---------------- kernel 1b: reduce uq partials -> softmax -> actions -------
__global__ __launch_bounds__(256) void k_actfin(
    const float* __restrict__ plogit, const float* __restrict__ b2v,
    float* __restrict__ actions)
{
    const size_t row = (size_t)blockIdx.x * 256 + threadIdx.x;
    const size_t stride = (size_t)NB * S_LEN * 4;
    float l0 = b2v[0], l1 = b2v[1], l2 = b2v[2];
#pragma unroll
    for (int uq = 0; uq < 4; ++uq) {
        const float4 p = *(const float4*)(plogit + row * 4 + uq * stride);
        l0 += p.x; l1 += p.y; l2 += p.z;
    }
    const float mx = fmaxf(l0, fmaxf(l1, l2));
    const float e0 = __expf(l0 - mx), e1 = __expf(l1 - mx), e2 = __expf(l2 - mx);
    const float inv = 1.f / (e0 + e1 + e2);
    *(float4*)(actions + row * 4) = make_float4(e0 * inv, e1 * inv, e2 * inv, 0.f);
}

// ---------------- fused kernel: scan (blocks 0..31) + prep transpose --------
union SPMem {
    float tile[64][65];
    struct {
        float4 actbuf[3][256];
        float  sums[2][256][16];
    } s;
};

__device__ __forceinline__ void rs_chunk(const float4* __restrict__ pb,
                                         float* __restrict__ so,
                                         float& rs, int lane)
{
    for (int w = 0; w < 32; ++w) {
        const int rtop = 255 - w * 8;
        const float4 e0 = pb[rtop],     e1 = pb[rtop - 1];
        const float4 e2 = pb[rtop - 2], e3 = pb[rtop - 3];
        const float4 e4 = pb[rtop - 4], e5 = pb[rtop - 5];
        const float4 e6 = pb[rtop - 6], e7 = pb[rtop - 7];
#define RS_STEP(E, k) do {                                                    \
        const float rsp = dpp_shr1_z(rs);                                     \
        const float s = (E).y * rsp;                                          \
        if (lane < 16) so[(rtop - (k)) * 16 + lane] = s;                      \
        rs = fmaf((E).x + (E).z, rs, s);                                      \
    } while (0)
        RS_STEP(e0, 0); RS_STEP(e1, 1); RS_STEP(e2, 2); RS_STEP(e3, 3);
        RS_STEP(e4, 4); RS_STEP(e5, 5); RS_STEP(e6, 6); RS_STEP(e7, 7);
#undef RS_STEP
    }
}

__device__ __forceinline__ void t_chunk(const float4* __restrict__ lb,
                                        const float* __restrict__ sp,
                                        float& T, bf16* __restrict__ obp,
                                        int tbase0, int w15)
{
    for (int w = 0; w < 32; ++w) {
        const int rtop = 255 - w * 8;
        const int tglob = tbase0 + rtop - 7;
        const float4 av0 = lb[rtop],     av1 = lb[rtop - 1];
        const float4 av2 = lb[rtop - 2], av3 = lb[rtop - 3];
        const float4 av4 = lb[rtop - 4], av5 = lb[rtop - 5];
        const float4 av6 = lb[rtop - 6], av7 = lb[rtop - 7];
        const float su0 = sp[rtop * 16],       su1 = sp[(rtop - 1) * 16];
        const float su2 = sp[(rtop - 2) * 16], su3 = sp[(rtop - 3) * 16];
        const float su4 = sp[(rtop - 4) * 16], su5 = sp[(rtop - 5) * 16];
        const float su6 = sp[(rtop - 6) * 16], su7 = sp[(rtop - 7) * 16];
        bf16x8 fr;
#define T_STEP(Av, Su, fi) do {                                               \
        const float a0 = (Av).x, a1 = (Av).y, a2 = (Av).z;                    \
        fr[fi] = (bf16)((a0 + a1) * T);                                       \
        const float nT = dpp_shl1_z(T);                                       \
        const float contrib = w15 ? (Su) : a0 * nT;                           \
        T = fmaf(a2, T, contrib);                                             \
    } while (0)
        T_STEP(av0, su0, 7); T_STEP(av1, su1, 6);
        T_STEP(av2, su2, 5); T_STEP(av3, su3, 4);
        T_STEP(av4, su4, 3); T_STEP(av5, su5, 2);
        T_STEP(av6, su6, 1); T_STEP(av7, su7, 0);
#undef T_STEP
        *(bf16x8*)(obp + tglob) = fr;
    }
}

__global__ __launch_bounds__(320) void k_scan_prep(
    const float* __restrict__ actions, bf16* __restrict__ wsT,
    const float* __restrict__ seq, bf16* __restrict__ tHi)
{
    __shared__ SPMem sm;
    const int tid = threadIdx.x;
    if (blockIdx.x < 32) {
        const int b = blockIdx.x;
        const int wid = tid >> 6;
        const int lane = tid & 63;
        const float4* actb = (const float4*)actions + (size_t)b * S_LEN;

        float rs = (lane == 0) ? 1.f : 0.f;
        float T = (wid == 0 && lane == 15) ? 1.f : 0.f;
        const int w15 = ((lane & 15) == 15) ? 1 : 0;
        bf16* obp = wsT + ((size_t)b * NP + wid * 64 + lane) * S_LEN;

        if (wid < 4) {
            gload16(actb + 1792 + wid * 64 + lane, &sm.s.actbuf[0][wid * 64]);
            gload16(actb + 1536 + wid * 64 + lane, &sm.s.actbuf[1][wid * 64]);
            asm volatile("s_waitcnt vmcnt(0)" ::: "memory");
        }
        __syncthreads();
        if (wid == 4) rs_chunk(sm.s.actbuf[0], &sm.s.sums[0][0][0], rs, lane);
        __syncthreads();

        int bufT = 0, bufP = 1, bufL = 2;
        for (int c = 0; c < 8; ++c) {
            if (wid < 4) {
                if (c < 6)
                    gload16(actb + (1280 - c * 256) + wid * 64 + lane,
                            &sm.s.actbuf[bufL][wid * 64]);
                t_chunk(sm.s.actbuf[bufT],
                        &sm.s.sums[c & 1][0][wid * 4 + (lane >> 4)],
                        T, obp, 1792 - c * 256, w15);
                asm volatile("s_waitcnt vmcnt(0)" ::: "memory");
            } else {
                if (c < 7)
                    rs_chunk(sm.s.actbuf[bufP], &sm.s.sums[(c + 1) & 1][0][0], rs, lane);
            }
            __syncthreads();
            const int t = bufT; bufT = bufP; bufP = bufL; bufL = t;
        }
        return;
    }
    // ---- prep transpose path ----
    const int bid = blockIdx.x - 32;
    const int b = bid >> 8;
    const int r = bid & 255;
    const int s0 = (r & 31) << 6;
    const int e0 = (r >> 5) << 6;
    const int tx = tid & 15, ty = (tid & 255) >> 4;
    const float* src = seq + ((size_t)b * S_LEN + s0) * NE + e0;
    if (tid < 256) {
#pragma unroll
        for (int i = 0; i < 4; ++i) {
            const int row = ty + i * 16;
            const float4 v = *(const float4*)(src + (size_t)row * NE + tx * 4);
            sm.tile[row][tx * 4 + 0] = v.x; sm.tile[row][tx * 4 + 1] = v.y;
            sm.tile[row][tx * 4 + 2] = v.z; sm.tile[row][tx * 4 + 3] = v.w;
        }
    }
    __syncthreads();
    if (tid < 256) {
        const int sx = tid & 7, ey = tid >> 3;
#pragma unroll
        for (int jj = 0; jj < 2; ++jj) {
            const int er = ey + jj * 32;
            bf16x8 oh;
#pragma unroll
            for (int q = 0; q < 8; ++q) oh[q] = (bf16)sm.tile[sx * 8 + q][er];
            *(bf16x8*)(tHi + ((size_t)b * NE + e0 + er) * S_LEN + s0 + sx * 8) = oh;
        }
    }
}

// ---------------- kernel 3: GEMM2 partials (2-way k-split, LDS-staged) ------
__global__ __launch_bounds__(256, 2) void k_gemm2(
    const bf16* __restrict__ wsT, const bf16* __restrict__ seqtH,
    float* __restrict__ part)
{
    __shared__ __align__(16) bf16 AL[2][4096];
    __shared__ __align__(16) bf16 BL[2][4096];
    const int tid = threadIdx.x;
    const int wid = tid >> 6;
    const int lane = tid & 63;
    const int lr = lane & 15, lg = lane >> 4;
    const int bid = blockIdx.x;
    const int b = bid >> 4;
    const int sub = bid & 15;
    const int kc = sub >> 3;
    const int p0 = ((sub >> 2) & 1) << 7;
    const int e0 = (sub & 3) << 7;

    const bf16* Abase = wsT + ((size_t)b * NP + p0) * S_LEN + kc * 1024;
    const bf16* Bbase = seqtH + ((size_t)b * NE + e0) * S_LEN + kc * 1024;
    const int lroff = lr * 64 + (lg ^ ((lr >> 1) & 3)) * 16;

    f32x4 acc[2][8];
#pragma unroll
    for (int i = 0; i < 2; ++i)
#pragma unroll
        for (int j = 0; j < 8; ++j) acc[i][j] = (f32x4)(0.f);

    stage_tile(Abase, S_LEN, AL[0], tid);
    stage_tile(Bbase, S_LEN, BL[0], tid);

#define G2_BODY(kt, buf) do {                                                 \
        __syncthreads();                                                      \
        bf16x8 af[2], bfv[8];                                                 \
        _Pragma("unroll") for (int i = 0; i < 2; ++i)                         \
            af[i] = *(const bf16x8*)((const char*)AL[buf]                     \
                     + (wid * 32 + i * 16) * 64 + lroff);                     \
        _Pragma("unroll") for (int j = 0; j < 8; ++j)                         \
            bfv[j] = *(const bf16x8*)((const char*)BL[buf] + j * 1024 + lroff);\
        __syncthreads();                                                      \
        if ((kt) < 31) {                                                      \
            stage_tile(Abase + ((kt) + 1) * 32, S_LEN, AL[(buf) ^ 1], tid);   \
            stage_tile(Bbase + ((kt) + 1) * 32, S_LEN, BL[(buf) ^ 1], tid);   \
        }                                                                     \
        _Pragma("unroll") for (int j = 0; j < 8; ++j) {                       \
            acc[0][j] = __builtin_amdgcn_mfma_f32_16x16x32_bf16(af[0], bfv[j], acc[0][j], 0, 0, 0); \
            acc[1][j] = __builtin_amdgcn_mfma_f32_16x16x32_bf16(af[1], bfv[j], acc[1][j], 0, 0, 0); \
        }                                                                     \
    } while (0)

    for (int kk = 0; kk < 16; ++kk) {
        G2_BODY(2 * kk, 0);
        G2_BODY(2 * kk + 1, 1);
    }
#undef G2_BODY

    float* obp = part + (((size_t)kc * NB + b) * NP + p0 + wid * 32) * NE + e0;
#pragma unroll
    for (int i = 0; i < 2; ++i)
#pragma unroll
        for (int j = 0; j < 8; ++j)
#pragma unroll
            for (int q = 0; q < 4; ++q)
                obp[(size_t)(i * 16 + lg * 4 + q) * NE + j * 16 + lr] = acc[i][j][q];
}

// ---------------- kernel 4: reduce the 2 partials ---------------------------
__global__ __launch_bounds__(256) void k_gred(
    const float* __restrict__ part, float* __restrict__ outp)
{
    const size_t i = ((size_t)blockIdx.x * 256 + threadIdx.x) * 4;
    const float4 p0 = *(const float4*)(part + i);
    const float4 p1 = *(const float4*)(part + ((size_t)NB * NP * NE) + i);
    *(float4*)(outp + i) = make_float4(p0.x + p1.x, p0.y + p1.y,
                                       p0.z + p1.z, p0.w + p1.w);
}

// ---------------- launch ----------------------------------------------------
extern "C" void kernel_launch(void* const* d_in, const int* in_sizes, int n_in,
                              void* d_out, int out_size, void* d_ws, size_t ws_size,
                              hipStream_t stream) {
    (void)in_sizes; (void)n_in; (void)out_size; (void)ws_size;
    const float* seq = (const float*)d_in[0];
    const float* w1  = (const float*)d_in[1];
    const float* b1  = (const float*)d_in[2];
    const float* w2  = (const float*)d_in[3];
    const float* b2  = (const float*)d_in[4];
    float* outp = (float*)d_out;

    char* ws = (char*)d_ws;
    bf16*  seqtH   = (bf16*)(ws);                        // 64 MB [b][e][s]
    bf16*  wsT     = (bf16*)(ws + (64ull << 20));        // 32 MB [b][p][t]
    float* actions = (float*)(ws + (96ull << 20));       // 1 MB  [b*S][4]
    bf16*  w1H     = (bf16*)(ws + (97ull << 20));        // 512 KB
    bf16*  w1L     = (bf16*)(ws + (97ull << 20) + (512u << 10)); // 512 KB
    float* part    = (float*)(ws + (98ull << 20));       // 32 MB [2][b][p][e]
    float* plogit  = (float*)(ws + (130ull << 20));      // 4 MB  [uq][row][4]

    hipLaunchKernelGGL(k_wconv, dim3(256),  dim3(256), 0, stream, w1, w1H, w1L);
    hipLaunchKernelGGL(k_gemm1, dim3(2048), dim3(256), 0, stream,
                       seq, w1H, w1L, b1, w2, plogit);
    hipLaunchKernelGGL(k_actfin, dim3(256), dim3(256), 0, stream,
                       plogit, b2, actions);
    hipLaunchKernelGGL(k_scan_prep, dim3(32 + 8192), dim3(320), 0, stream,
                       actions, wsT, seq, seqtH);
    hipLaunchKernelGGL(k_gemm2, dim3(512),  dim3(256), 0, stream, wsT, seqtH, part);
    hipLaunchKernelGGL(k_gred,  dim3(4096), dim3(256), 0, stream, part, outp);
}

// Round 11
// 287.658 us; speedup vs baseline: 1.4889x; 1.1786x over previous
//
#include <hip/hip_runtime.h>
#include <stdint.h>

#define S_LEN 2048
#define NB 32
#define NE 512
#define NU 512
#define NP 256

typedef __bf16 bf16;
typedef __bf16 bf16x8 __attribute__((ext_vector_type(8)));
typedef __bf16 bf16x4 __attribute__((ext_vector_type(4)));
typedef float f32x4 __attribute__((ext_vector_type(4)));
typedef float f32x8 __attribute__((ext_vector_type(8)));

__device__ __forceinline__ void gload16(const void* g, void* l) {
    __builtin_amdgcn_global_load_lds(
        (__attribute__((address_space(1))) void*)g,
        (__attribute__((address_space(3))) void*)l, 16, 0, 0);
}

// DPP helpers (HW-verified rounds 4-6)
__device__ __forceinline__ float dpp_shr1_z(float x) {
    return __builtin_bit_cast(float, __builtin_amdgcn_update_dpp(
        0, __builtin_bit_cast(int, x), 0x111, 0xF, 0xF, true));
}
__device__ __forceinline__ float dpp_shl1_z(float x) {
    return __builtin_bit_cast(float, __builtin_amdgcn_update_dpp(
        0, __builtin_bit_cast(int, x), 0x101, 0xF, 0xF, true));
}

// Stage a 128-row x 32-col bf16 tile (row stride SR) into 8KB LDS (256 thr);
// self-inverse k-quad permutation q = (c&3) ^ ((row>>1)&3).
__device__ __forceinline__ void stage_tile(const bf16* __restrict__ src, int SR,
                                           bf16* lds, int tid) {
#pragma unroll
    for (int rnd = 0; rnd < 2; ++rnd) {
        const int c = rnd * 256 + tid;
        const int row = c >> 2;
        const int q = (c & 3) ^ ((c >> 3) & 3);
        gload16(src + (size_t)row * SR + q * 8, lds + c * 8);
    }
}

// ---------------- kernel 0b: w1 fp32 -> bf16 hi/lo --------------------------
__global__ __launch_bounds__(256) void k_wconv(
    const float* __restrict__ w1, bf16* __restrict__ wHi, bf16* __restrict__ wLo)
{
    const int i = (blockIdx.x * 256 + threadIdx.x) * 4;
    const float4 v = *(const float4*)(w1 + i);
    const float vv[4] = {v.x, v.y, v.z, v.w};
    bf16x4 oh, ol;
#pragma unroll
    for (int q = 0; q < 4; ++q) {
        const bf16 hb = (bf16)vv[q];
        oh[q] = hb;
        ol[q] = (bf16)(vv[q] - (float)hb);
    }
    *(bf16x4*)(wHi + i) = oh;
    *(bf16x4*)(wLo + i) = ol;
}

// ---------------- kernel 1: GEMM1 + silu + logits + softmax -----------------
// Round-6 configuration (measured 159us): 256 thr / 4 waves, wave = 32 rows x
// 128 u; block = 128 rows; 4 u-panels in-loop; A = seq fp32 direct per-lane
// (hi/lo split in regs, 1-step prefetch); B = w1 hi/lo LDS dbuf.
// Only change vs r6: A prefetch issued BEFORE B stage (longer-latency first).
__global__ __launch_bounds__(256, 2) void k_gemm1(
    const float* __restrict__ seq,
    const bf16* __restrict__ w1H, const bf16* __restrict__ w1L,
    const float* __restrict__ b1v, const float* __restrict__ w2,
    const float* __restrict__ b2v, float* __restrict__ actions)
{
    __shared__ __align__(16) bf16 BhL[2][4096];
    __shared__ __align__(16) bf16 BlL[2][4096];
    const int tid = threadIdx.x;
    const int wid = tid >> 6;
    const int lane = tid & 63;
    const int lr = lane & 15, lg = lane >> 4;
    const int m0 = blockIdx.x << 7;

    const float* arow0 = seq + (size_t)(m0 + wid * 32 + lr) * NE + lg * 8;
    const float* arow1 = arow0 + 16 * NE;
    const int lroff = lr * 64 + (lg ^ ((lr >> 1) & 3)) * 16;

    float plog[3][2][4];
#pragma unroll
    for (int a = 0; a < 3; ++a)
#pragma unroll
        for (int i = 0; i < 2; ++i)
#pragma unroll
            for (int q = 0; q < 4; ++q) plog[a][i][q] = 0.f;

    f32x4 acc[2][8];
    stage_tile(w1H, NE, BhL[0], tid);
    stage_tile(w1L, NE, BlL[0], tid);
    f32x8 Aa0 = *(const f32x8*)(arow0);
    f32x8 Aa1 = *(const f32x8*)(arow1);
    f32x8 Ab0, Ab1;

#define G1_BODY(g, buf, Ac0, Ac1, An0, An1) do {                              \
        __syncthreads();                                                      \
        if (((g) & 15) == 0) {                                                \
            _Pragma("unroll") for (int i = 0; i < 2; ++i)                     \
            _Pragma("unroll") for (int j = 0; j < 8; ++j)                     \
                acc[i][j] = (f32x4)(0.f);                                     \
        }                                                                     \
        bf16x8 bh[8], bl[8];                                                  \
        _Pragma("unroll") for (int j = 0; j < 8; ++j) {                       \
            bh[j] = *(const bf16x8*)((const char*)BhL[buf] + j * 1024 + lroff);\
            bl[j] = *(const bf16x8*)((const char*)BlL[buf] + j * 1024 + lroff);\
        }                                                                     \
        __syncthreads();                                                      \
        if ((g) < 63) {                                                       \
            const int gn = (g) + 1;                                           \
            const int u0n = (gn >> 4) << 7;                                   \
            const int k0n = (gn & 15) << 5;                                   \
            An0 = *(const f32x8*)(arow0 + k0n);                               \
            An1 = *(const f32x8*)(arow1 + k0n);                               \
            stage_tile(w1H + (size_t)u0n * NE + k0n, NE, BhL[(buf) ^ 1], tid);\
            stage_tile(w1L + (size_t)u0n * NE + k0n, NE, BlL[(buf) ^ 1], tid);\
        }                                                                     \
        bf16x8 Ah0, Al0, Ah1, Al1;                                            \
        _Pragma("unroll") for (int q = 0; q < 8; ++q) {                       \
            const bf16 h0 = (bf16)Ac0[q];                                     \
            Ah0[q] = h0; Al0[q] = (bf16)(Ac0[q] - (float)h0);                 \
            const bf16 h1 = (bf16)Ac1[q];                                     \
            Ah1[q] = h1; Al1[q] = (bf16)(Ac1[q] - (float)h1);                 \
        }                                                                     \
        _Pragma("unroll") for (int j = 0; j < 8; ++j) {                       \
            acc[0][j] = __builtin_amdgcn_mfma_f32_16x16x32_bf16(Ah0, bh[j], acc[0][j], 0, 0, 0); \
            acc[0][j] = __builtin_amdgcn_mfma_f32_16x16x32_bf16(Ah0, bl[j], acc[0][j], 0, 0, 0); \
            acc[0][j] = __builtin_amdgcn_mfma_f32_16x16x32_bf16(Al0, bh[j], acc[0][j], 0, 0, 0); \
            acc[1][j] = __builtin_amdgcn_mfma_f32_16x16x32_bf16(Ah1, bh[j], acc[1][j], 0, 0, 0); \
            acc[1][j] = __builtin_amdgcn_mfma_f32_16x16x32_bf16(Ah1, bl[j], acc[1][j], 0, 0, 0); \
            acc[1][j] = __builtin_amdgcn_mfma_f32_16x16x32_bf16(Al1, bh[j], acc[1][j], 0, 0, 0); \
        }                                                                     \
        if (((g) & 15) == 15) {                                               \
            const int u0 = ((g) >> 4) << 7;                                   \
            _Pragma("unroll") for (int j = 0; j < 8; ++j) {                   \
                const int col = u0 + j * 16 + lr;                             \
                const float b1c = b1v[col];                                   \
                const float w20 = w2[col], w21 = w2[NU + col], w22 = w2[2 * NU + col]; \
                _Pragma("unroll") for (int i = 0; i < 2; ++i)                 \
                _Pragma("unroll") for (int q = 0; q < 4; ++q) {               \
                    const float x = acc[i][j][q] + b1c;                       \
                    const float hgate = x / (1.f + __expf(-x));               \
                    plog[0][i][q] = fmaf(hgate, w20, plog[0][i][q]);          \
                    plog[1][i][q] = fmaf(hgate, w21, plog[1][i][q]);          \
                    plog[2][i][q] = fmaf(hgate, w22, plog[2][i][q]);          \
                }                                                             \
            }                                                                 \
        }                                                                     \
    } while (0)

    for (int gg = 0; gg < 32; ++gg) {
        G1_BODY(2 * gg, 0, Aa0, Aa1, Ab0, Ab1);
        G1_BODY(2 * gg + 1, 1, Ab0, Ab1, Aa0, Aa1);
    }
#undef G1_BODY

#pragma unroll
    for (int m = 1; m < 16; m <<= 1) {
#pragma unroll
        for (int a = 0; a < 3; ++a)
#pragma unroll
            for (int i = 0; i < 2; ++i)
#pragma unroll
                for (int q = 0; q < 4; ++q)
                    plog[a][i][q] += __shfl_xor(plog[a][i][q], m);
    }
    const float bb0 = b2v[0], bb1 = b2v[1], bb2 = b2v[2];
    if (lr == 0) {
#pragma unroll
        for (int i = 0; i < 2; ++i)
#pragma unroll
            for (int q = 0; q < 4; ++q) {
                const int row = m0 + wid * 32 + i * 16 + lg * 4 + q;
                const float l0 = plog[0][i][q] + bb0;
                const float l1 = plog[1][i][q] + bb1;
                const float l2 = plog[2][i][q] + bb2;
                const float mx = fmaxf(l0, fmaxf(l1, l2));
                const float e0 = __expf(l0 - mx), e1 = __expf(l1 - mx), e2 = __expf(l2 - mx);
                const float inv = 1.f / (e0 + e1 + e2);
                *(float4*)(actions + (size_t)row * 4) = make_float4(e0 * inv, e1 * inv, e2 * inv, 0.f);
            }
    }
}

// ---------------- fused kernel: scan (blocks 0..31) + prep transpose --------
union SPMem {
    float tile[64][65];
    struct {
        float4 actbuf[3][256];
        float  sums[2][256][16];
    } s;
};

__device__ __forceinline__ void rs_chunk(const float4* __restrict__ pb,
                                         float* __restrict__ so,
                                         float& rs, int lane)
{
    for (int w = 0; w < 32; ++w) {
        const int rtop = 255 - w * 8;
        const float4 e0 = pb[rtop],     e1 = pb[rtop - 1];
        const float4 e2 = pb[rtop - 2], e3 = pb[rtop - 3];
        const float4 e4 = pb[rtop - 4], e5 = pb[rtop - 5];
        const float4 e6 = pb[rtop - 6], e7 = pb[rtop - 7];
#define RS_STEP(E, k) do {                                                    \
        const float rsp = dpp_shr1_z(rs);                                     \
        const float s = (E).y * rsp;                                          \
        if (lane < 16) so[(rtop - (k)) * 16 + lane] = s;                      \
        rs = fmaf((E).x + (E).z, rs, s);                                      \
    } while (0)
        RS_STEP(e0, 0); RS_STEP(e1, 1); RS_STEP(e2, 2); RS_STEP(e3, 3);
        RS_STEP(e4, 4); RS_STEP(e5, 5); RS_STEP(e6, 6); RS_STEP(e7, 7);
#undef RS_STEP
    }
}

__device__ __forceinline__ void t_chunk(const float4* __restrict__ lb,
                                        const float* __restrict__ sp,
                                        float& T, bf16* __restrict__ obp,
                                        int tbase0, int w15)
{
    for (int w = 0; w < 32; ++w) {
        const int rtop = 255 - w * 8;
        const int tglob = tbase0 + rtop - 7;
        const float4 av0 = lb[rtop],     av1 = lb[rtop - 1];
        const float4 av2 = lb[rtop - 2], av3 = lb[rtop - 3];
        const float4 av4 = lb[rtop - 4], av5 = lb[rtop - 5];
        const float4 av6 = lb[rtop - 6], av7 = lb[rtop - 7];
        const float su0 = sp[rtop * 16],       su1 = sp[(rtop - 1) * 16];
        const float su2 = sp[(rtop - 2) * 16], su3 = sp[(rtop - 3) * 16];
        const float su4 = sp[(rtop - 4) * 16], su5 = sp[(rtop - 5) * 16];
        const float su6 = sp[(rtop - 6) * 16], su7 = sp[(rtop - 7) * 16];
        bf16x8 fr;
#define T_STEP(Av, Su, fi) do {                                               \
        const float a0 = (Av).x, a1 = (Av).y, a2 = (Av).z;                    \
        fr[fi] = (bf16)((a0 + a1) * T);                                       \
        const float nT = dpp_shl1_z(T);                                       \
        const float contrib = w15 ? (Su) : a0 * nT;                           \
        T = fmaf(a2, T, contrib);                                             \
    } while (0)
        T_STEP(av0, su0, 7); T_STEP(av1, su1, 6);
        T_STEP(av2, su2, 5); T_STEP(av3, su3, 4);
        T_STEP(av4, su4, 3); T_STEP(av5, su5, 2);
        T_STEP(av6, su6, 1); T_STEP(av7, su7, 0);
#undef T_STEP
        *(bf16x8*)(obp + tglob) = fr;
    }
}

__global__ __launch_bounds__(320) void k_scan_prep(
    const float* __restrict__ actions, bf16* __restrict__ wsT,
    const float* __restrict__ seq, bf16* __restrict__ tHi)
{
    __shared__ SPMem sm;
    const int tid = threadIdx.x;
    if (blockIdx.x < 32) {
        const int b = blockIdx.x;
        const int wid = tid >> 6;
        const int lane = tid & 63;
        const float4* actb = (const float4*)actions + (size_t)b * S_LEN;

        float rs = (lane == 0) ? 1.f : 0.f;
        float T = (wid == 0 && lane == 15) ? 1.f : 0.f;
        const int w15 = ((lane & 15) == 15) ? 1 : 0;
        bf16* obp = wsT + ((size_t)b * NP + wid * 64 + lane) * S_LEN;

        if (wid < 4) {
            gload16(actb + 1792 + wid * 64 + lane, &sm.s.actbuf[0][wid * 64]);
            gload16(actb + 1536 + wid * 64 + lane, &sm.s.actbuf[1][wid * 64]);
            asm volatile("s_waitcnt vmcnt(0)" ::: "memory");
        }
        __syncthreads();
        if (wid == 4) rs_chunk(sm.s.actbuf[0], &sm.s.sums[0][0][0], rs, lane);
        __syncthreads();

        int bufT = 0, bufP = 1, bufL = 2;
        for (int c = 0; c < 8; ++c) {
            if (wid < 4) {
                if (c < 6)
                    gload16(actb + (1280 - c * 256) + wid * 64 + lane,
                            &sm.s.actbuf[bufL][wid * 64]);
                t_chunk(sm.s.actbuf[bufT],
                        &sm.s.sums[c & 1][0][wid * 4 + (lane >> 4)],
                        T, obp, 1792 - c * 256, w15);
                asm volatile("s_waitcnt vmcnt(0)" ::: "memory");
            } else {
                if (c < 7)
                    rs_chunk(sm.s.actbuf[bufP], &sm.s.sums[(c + 1) & 1][0][0], rs, lane);
            }
            __syncthreads();
            const int t = bufT; bufT = bufP; bufP = bufL; bufL = t;
        }
        return;
    }
    // ---- prep transpose path ----
    const int bid = blockIdx.x - 32;
    const int b = bid >> 8;
    const int r = bid & 255;
    const int s0 = (r & 31) << 6;
    const int e0 = (r >> 5) << 6;
    const int tx = tid & 15, ty = (tid & 255) >> 4;
    const float* src = seq + ((size_t)b * S_LEN + s0) * NE + e0;
    if (tid < 256) {
#pragma unroll
        for (int i = 0; i < 4; ++i) {
            const int row = ty + i * 16;
            const float4 v = *(const float4*)(src + (size_t)row * NE + tx * 4);
            sm.tile[row][tx * 4 + 0] = v.x; sm.tile[row][tx * 4 + 1] = v.y;
            sm.tile[row][tx * 4 + 2] = v.z; sm.tile[row][tx * 4 + 3] = v.w;
        }
    }
    __syncthreads();
    if (tid < 256) {
        const int sx = tid & 7, ey = tid >> 3;
#pragma unroll
        for (int jj = 0; jj < 2; ++jj) {
            const int er = ey + jj * 32;
            bf16x8 oh;
#pragma unroll
            for (int q = 0; q < 8; ++q) oh[q] = (bf16)sm.tile[sx * 8 + q][er];
            *(bf16x8*)(tHi + ((size_t)b * NE + e0 + er) * S_LEN + s0 + sx * 8) = oh;
        }
    }
}

// ---------------- kernel 3: GEMM2 partials (2-way k-split, LDS-staged) ------
__global__ __launch_bounds__(256, 2) void k_gemm2(
    const bf16* __restrict__ wsT, const bf16* __restrict__ seqtH,
    float* __restrict__ part)
{
    __shared__ __align__(16) bf16 AL[2][4096];
    __shared__ __align__(16) bf16 BL[2][4096];
    const int tid = threadIdx.x;
    const int wid = tid >> 6;
    const int lane = tid & 63;
    const int lr = lane & 15, lg = lane >> 4;
    const int bid = blockIdx.x;
    const int b = bid >> 4;
    const int sub = bid & 15;
    const int kc = sub >> 3;
    const int p0 = ((sub >> 2) & 1) << 7;
    const int e0 = (sub & 3) << 7;

    const bf16* Abase = wsT + ((size_t)b * NP + p0) * S_LEN + kc * 1024;
    const bf16* Bbase = seqtH + ((size_t)b * NE + e0) * S_LEN + kc * 1024;
    const int lroff = lr * 64 + (lg ^ ((lr >> 1) & 3)) * 16;

    f32x4 acc[2][8];
#pragma unroll
    for (int i = 0; i < 2; ++i)
#pragma unroll
        for (int j = 0; j < 8; ++j) acc[i][j] = (f32x4)(0.f);

    stage_tile(Abase, S_LEN, AL[0], tid);
    stage_tile(Bbase, S_LEN, BL[0], tid);

#define G2_BODY(kt, buf) do {                                                 \
        __syncthreads();                                                      \
        bf16x8 af[2], bfv[8];                                                 \
        _Pragma("unroll") for (int i = 0; i < 2; ++i)                         \
            af[i] = *(const bf16x8*)((const char*)AL[buf]                     \
                     + (wid * 32 + i * 16) * 64 + lroff);                     \
        _Pragma("unroll") for (int j = 0; j < 8; ++j)                         \
            bfv[j] = *(const bf16x8*)((const char*)BL[buf] + j * 1024 + lroff);\
        __syncthreads();                                                      \
        if ((kt) < 31) {                                                      \
            stage_tile(Abase + ((kt) + 1) * 32, S_LEN, AL[(buf) ^ 1], tid);   \
            stage_tile(Bbase + ((kt) + 1) * 32, S_LEN, BL[(buf) ^ 1], tid);   \
        }                                                                     \
        _Pragma("unroll") for (int j = 0; j < 8; ++j) {                       \
            acc[0][j] = __builtin_amdgcn_mfma_f32_16x16x32_bf16(af[0], bfv[j], acc[0][j], 0, 0, 0); \
            acc[1][j] = __builtin_amdgcn_mfma_f32_16x16x32_bf16(af[1], bfv[j], acc[1][j], 0, 0, 0); \
        }                                                                     \
    } while (0)

    for (int kk = 0; kk < 16; ++kk) {
        G2_BODY(2 * kk, 0);
        G2_BODY(2 * kk + 1, 1);
    }
#undef G2_BODY

    float* obp = part + (((size_t)kc * NB + b) * NP + p0 + wid * 32) * NE + e0;
#pragma unroll
    for (int i = 0; i < 2; ++i)
#pragma unroll
        for (int j = 0; j < 8; ++j)
#pragma unroll
            for (int q = 0; q < 4; ++q)
                obp[(size_t)(i * 16 + lg * 4 + q) * NE + j * 16 + lr] = acc[i][j][q];
}

// ---------------- kernel 4: reduce the 2 partials ---------------------------
__global__ __launch_bounds__(256) void k_gred(
    const float* __restrict__ part, float* __restrict__ outp)
{
    const size_t i = ((size_t)blockIdx.x * 256 + threadIdx.x) * 4;
    const float4 p0 = *(const float4*)(part + i);
    const float4 p1 = *(const float4*)(part + ((size_t)NB * NP * NE) + i);
    *(float4*)(outp + i) = make_float4(p0.x + p1.x, p0.y + p1.y,
                                       p0.z + p1.z, p0.w + p1.w);
}

// ---------------- launch ----------------------------------------------------
extern "C" void kernel_launch(void* const* d_in, const int* in_sizes, int n_in,
                              void* d_out, int out_size, void* d_ws, size_t ws_size,
                              hipStream_t stream) {
    (void)in_sizes; (void)n_in; (void)out_size; (void)ws_size;
    const float* seq = (const float*)d_in[0];
    const float* w1  = (const float*)d_in[1];
    const float* b1  = (const float*)d_in[2];
    const float* w2  = (const float*)d_in[3];
    const float* b2  = (const float*)d_in[4];
    float* outp = (float*)d_out;

    char* ws = (char*)d_ws;
    bf16*  seqtH   = (bf16*)(ws);                        // 64 MB [b][e][s]
    bf16*  wsT     = (bf16*)(ws + (64ull << 20));        // 32 MB [b][p][t]
    float* actions = (float*)(ws + (96ull << 20));       // 1 MB  [b*S][4]
    bf16*  w1H     = (bf16*)(ws + (97ull << 20));        // 512 KB
    bf16*  w1L     = (bf16*)(ws + (97ull << 20) + (512u << 10)); // 512 KB
    float* part    = (float*)(ws + (98ull << 20));       // 32 MB [2][b][p][e]

    hipLaunchKernelGGL(k_wconv, dim3(256),  dim3(256), 0, stream, w1, w1H, w1L);
    hipLaunchKernelGGL(k_gemm1, dim3(512),  dim3(256), 0, stream,
                       seq, w1H, w1L, b1, w2, b2, actions);
    hipLaunchKernelGGL(k_scan_prep, dim3(32 + 8192), dim3(320), 0, stream,
                       actions, wsT, seq, seqtH);
    hipLaunchKernelGGL(k_gemm2, dim3(512),  dim3(256), 0, stream, wsT, seqtH, part);
    hipLaunchKernelGGL(k_gred,  dim3(4096), dim3(256), 0, stream, part, outp);
}